// Round 5
// baseline (172.258 us; speedup 1.0000x reference)
//
#include <hip/hip_runtime.h>
#include <math.h>

// Dims (fixed by the problem)
#define B_SZ 2
#define L_SZ 384
#define D_SZ 384
#define S_SZ 384
#define BLK_ELEMS (L_SZ * D_SZ)        // 147456 per batch
#define TOT_ELEMS (B_SZ * L_SZ * D_SZ) // 294912
#define LOG2E 1.4426950408889634f

typedef __attribute__((ext_vector_type(8))) short bf16x8;
typedef __attribute__((ext_vector_type(4))) float f32x4;
typedef __attribute__((ext_vector_type(2))) unsigned int u32x2;

__device__ __forceinline__ float fexp2(float x) {
  return __builtin_amdgcn_exp2f(x);
}
__device__ __forceinline__ float softplus_f(float z) {
  return (z > 20.f) ? z : log1pf(__expf(z));
}
__device__ __forceinline__ unsigned short f2bf(float f) {  // RNE f32->bf16
  unsigned int u = __float_as_uint(f);
  return (unsigned short)((u + 0x7FFFu + ((u >> 16) & 1u)) >> 16);
}
#define PIPELINE_FENCE() asm volatile("" ::: "memory")

// 8x f32 -> 8x bf16 (RNE) via v_cvt_pk_bf16_f32 (gfx950 VALU, no hazard
// class — unlike permlane, plain VALU asm is safe). D.lo=bf16(S0),
// D.hi=bf16(S1) matches little-endian element order.
__device__ __forceinline__ bf16x8 cvt8(const float* p) {
  const f32x4 v0 = *(const f32x4*)p;
  const f32x4 v1 = *(const f32x4*)(p + 4);
  union { unsigned int u[4]; bf16x8 v; } r;
  asm("v_cvt_pk_bf16_f32 %0, %1, %2" : "=v"(r.u[0]) : "v"(v0[0]), "v"(v0[1]));
  asm("v_cvt_pk_bf16_f32 %0, %1, %2" : "=v"(r.u[1]) : "v"(v0[2]), "v"(v0[3]));
  asm("v_cvt_pk_bf16_f32 %0, %1, %2" : "=v"(r.u[2]) : "v"(v1[0]), "v"(v1[1]));
  asm("v_cvt_pk_bf16_f32 %0, %1, %2" : "=v"(r.u[3]) : "v"(v1[2]), "v"(v1[3]));
  return r.v;
}

// DPP lane exchange (VALU pipe — no DS latency). CTRL: 0x140=row_mirror
// (xor15), 0x141=row_half_mirror (xor7), 0xB1=quad_perm[1,0,3,2] (xor1),
// 0x4E=quad_perm[2,3,0,1] (xor2).
template <int CTRL>
__device__ __forceinline__ float dpp_mov(float v) {
  return __int_as_float(
      __builtin_amdgcn_update_dpp(0, __float_as_int(v), CTRL, 0xF, 0xF, true));
}

// r + shfl_xor(r,16)/(r,32) in ALL lanes via permlane*_swap BUILTINS
// (raw asm hit the gfx950 VALU-write->permlane wait-state hazard, v13).
__device__ __forceinline__ float fold_xor16(float r) {
#if __has_builtin(__builtin_amdgcn_permlane16_swap)
  const unsigned ru = __float_as_uint(r);
  u32x2 p = __builtin_amdgcn_permlane16_swap(ru, ru, false, false);
  return __uint_as_float(p[0]) + __uint_as_float(p[1]);
#else
  return r + __shfl_xor(r, 16, 64);
#endif
}
__device__ __forceinline__ float fold_xor32(float r) {
#if __has_builtin(__builtin_amdgcn_permlane32_swap)
  const unsigned ru = __float_as_uint(r);
  u32x2 p = __builtin_amdgcn_permlane32_swap(ru, ru, false, false);
  return __uint_as_float(p[0]) + __uint_as_float(p[1]);
#else
  return r + __shfl_xor(r, 32, 64);
#endif
}

// ---------------------------------------------------------------------------
// LDS-staged dual MFMA NT-GEMM. MODE 1: A is f32 (x), epilogue softplus+bf16.
// MODE 2: A is bf16 (xdbl), epilogue f32+f32. W1/W2 are always f32 now —
// conversion fused into staging (cvt_bf16_kernel deleted; one less launch).
// ---------------------------------------------------------------------------
template <int MODE>
__global__ __launch_bounds__(128, 2) void mfma_dual_gemm(
    const void* __restrict__ Av, const float* __restrict__ W1,
    const float* __restrict__ W2, const float* __restrict__ bias,
    float* __restrict__ O1, void* __restrict__ O2v) {
  __shared__ unsigned short sA[32 * 392];
  __shared__ unsigned short sW1[16 * 392];
  __shared__ unsigned short sW2[16 * 392];

  const int t = threadIdx.x;
  const int wv = t >> 6;
  const int lane = t & 63;
  const int nt = blockIdx.x;
  const int mrow = blockIdx.y;

  const float* W1b = W1 + nt * 16 * 384;
  const float* W2b = W2 + nt * 16 * 384;

  if constexpr (MODE == 1) {
    const float* Ab = (const float*)Av + mrow * 32 * 384;
#pragma unroll
    for (int it = 0; it < 12; ++it) {
      const int id = t + it * 128;
      const int row = id / 48, col = id - row * 48;
      *(bf16x8*)&sA[row * 392 + col * 8] = cvt8(Ab + id * 8);
    }
  } else {
    const unsigned short* Ab = (const unsigned short*)Av + mrow * 32 * 384;
#pragma unroll
    for (int it = 0; it < 12; ++it) {
      const int id = t + it * 128;
      const int row = id / 48, col = id - row * 48;
      *(bf16x8*)&sA[row * 392 + col * 8] = *(const bf16x8*)(Ab + id * 8);
    }
  }
#pragma unroll
  for (int it = 0; it < 6; ++it) {
    const int id = t + it * 128;
    const int row = id / 48, col = id - row * 48;
    *(bf16x8*)&sW1[row * 392 + col * 8] = cvt8(W1b + id * 8);
    *(bf16x8*)&sW2[row * 392 + col * 8] = cvt8(W2b + id * 8);
  }
  __syncthreads();

  const int rc = lane & 15;
  const int quad = lane >> 4;
  bf16x8 af[12], w1f[12], w2f[12];
#pragma unroll
  for (int kt = 0; kt < 12; ++kt) {
    af[kt] = *(const bf16x8*)&sA[(wv * 16 + rc) * 392 + quad * 8 + kt * 32];
    w1f[kt] = *(const bf16x8*)&sW1[rc * 392 + quad * 8 + kt * 32];
    w2f[kt] = *(const bf16x8*)&sW2[rc * 392 + quad * 8 + kt * 32];
  }
  PIPELINE_FENCE();
  f32x4 acc1 = {0.f, 0.f, 0.f, 0.f};
  f32x4 acc2 = {0.f, 0.f, 0.f, 0.f};
#pragma unroll
  for (int kt = 0; kt < 12; ++kt) {
    acc1 = __builtin_amdgcn_mfma_f32_16x16x32_bf16(af[kt], w1f[kt], acc1, 0, 0, 0);
    acc2 = __builtin_amdgcn_mfma_f32_16x16x32_bf16(af[kt], w2f[kt], acc2, 0, 0, 0);
  }
  const int col = nt * 16 + rc;
  const int row0 = mrow * 32 + wv * 16 + quad * 4;
  if constexpr (MODE == 1) {
    unsigned short* O2 = (unsigned short*)O2v;
    const float bb = bias[col];
#pragma unroll
    for (int r = 0; r < 4; ++r) {
      O1[(row0 + r) * 384 + col] = softplus_f(acc1[r] + bb);
      O2[(row0 + r) * 384 + col] = f2bf(acc2[r]);
    }
  } else {
    float* O2 = (float*)O2v;
#pragma unroll
    for (int r = 0; r < 4; ++r) {
      O1[(row0 + r) * 384 + col] = acc1[r];
      O2[(row0 + r) * 384 + col] = acc2[r];
    }
  }
}

// ---------------------------------------------------------------------------
// Conv + SiLU + transpose; now ALSO transposes Cm [b,l,s] -> Cm_t [b,s,l]
// (same tile machinery) so the scan's C reads become 2 contiguous dwordx4
// per lane instead of 8 scattered dword loads.
// ---------------------------------------------------------------------------
__global__ __launch_bounds__(256) void conv_tr_kernel(
    const float* __restrict__ x, const float* __restrict__ cw,
    const float* __restrict__ cb, const float* __restrict__ dt,
    const float* __restrict__ Cmi,
    float* __restrict__ u, float* __restrict__ dt_t,
    float* __restrict__ dtu_t, float* __restrict__ Cm_t) {
  __shared__ float Tdt[32][33];
  __shared__ float Tdu[32][33];
  __shared__ float Tcm[32][33];
  const int tx = threadIdx.x;
  const int ty = threadIdx.y;
  const int b = blockIdx.z;
  const int i0 = blockIdx.y * 32;
  const int l0 = blockIdx.x * 32;
  const int gi = i0 + tx;
  const float cbv = cb[gi];
  const float cw0 = cw[gi * 4 + 0], cw1 = cw[gi * 4 + 1];
  const float cw2 = cw[gi * 4 + 2], cw3 = cw[gi * 4 + 3];
#pragma unroll
  for (int r = 0; r < 4; ++r) {
    const int l = l0 + ty + 8 * r;
    float acc = cbv;
    const float x3 = x[(b * L_SZ + l) * D_SZ + gi];
    const float x2 = (l >= 1) ? x[(b * L_SZ + l - 1) * D_SZ + gi] : 0.f;
    const float x1 = (l >= 2) ? x[(b * L_SZ + l - 2) * D_SZ + gi] : 0.f;
    const float x0 = (l >= 3) ? x[(b * L_SZ + l - 3) * D_SZ + gi] : 0.f;
    acc = fmaf(x0, cw0, acc);
    acc = fmaf(x1, cw1, acc);
    acc = fmaf(x2, cw2, acc);
    acc = fmaf(x3, cw3, acc);
    const float uv = acc / (1.f + __expf(-acc));
    const int off = (b * L_SZ + l) * D_SZ + gi;
    u[off] = uv;
    const float dtv = dt[off];
    Tdt[ty + 8 * r][tx] = dtv;
    Tdu[ty + 8 * r][tx] = dtv * uv;
    Tcm[ty + 8 * r][tx] = Cmi[off];  // S_SZ == D_SZ: same tile coords
  }
  __syncthreads();
#pragma unroll
  for (int r = 0; r < 4; ++r) {
    const int il = ty + 8 * r;
    const int off = (b * D_SZ + i0 + il) * L_SZ + l0 + tx;
    dt_t[off] = Tdt[tx][il];
    dtu_t[off] = Tdu[tx][il];
    Cm_t[off] = Tcm[tx][il];
  }
}

// ---------------------------------------------------------------------------
// Selective scan v15. History: v12 XCD swizzle fixed FETCH (10.3->4.7MB),
// no time change. v14 removed all DS ops + merged waves: no time change.
// VALUBusy pinned ~51% = 2x the pure VALU-issue demand -> waves stall in a
// correlated way. Remaining suspect: 12 VMEM instr/chunk -> 36-38
// outstanding per wave; if the per-wave VMEM queue is shallower, the wave
// blocks AT LOAD ISSUE (invisible to prefetch-depth math, invariant to all
// prior changes). Fix: Cm transposed to [b,s,l] (conv_tr), so per chunk:
// 2 uniform dwordx4 (dt) + 2 (dtu) + 2 per-lane dwordx4 (Cm_t row) =
// 6 instr, max ~20 outstanding. WAIT = vmcnt(12) (12 newer loads after the
// waited chunk's; exact in prologue, slightly conservative in steady state).
// Grid back to v12 shape (4608 x 64, best measured).
// ---------------------------------------------------------------------------
struct ChunkS {
  f32x4 d0, d1, u0, u1, c0, c1;
};

#define LOAD_CHUNK(K, CMT, DTB, DUB)                                           \
  {                                                                            \
    asm volatile("global_load_dwordx4 %0, %1, off" : "=v"(K.d0) : "v"(DTB));   \
    asm volatile("global_load_dwordx4 %0, %1, off offset:16"                   \
                 : "=v"(K.d1) : "v"(DTB));                                     \
    asm volatile("global_load_dwordx4 %0, %1, off" : "=v"(K.u0) : "v"(DUB));   \
    asm volatile("global_load_dwordx4 %0, %1, off offset:16"                   \
                 : "=v"(K.u1) : "v"(DUB));                                     \
    asm volatile("global_load_dwordx4 %0, %1, off" : "=v"(K.c0) : "v"(CMT));   \
    asm volatile("global_load_dwordx4 %0, %1, off offset:16"                   \
                 : "=v"(K.c1) : "v"(CMT));                                     \
  }

#define WAIT_CHUNK(K)                                                          \
  asm volatile("s_waitcnt vmcnt(12)"                                           \
               : "+v"(K.d0), "+v"(K.d1), "+v"(K.u0), "+v"(K.u1),               \
                 "+v"(K.c0), "+v"(K.c1))

#define ADV_BASES()                                                            \
  { cmt += 8; dtB += 8; duB += 8; }

__global__ __launch_bounds__(64, 4) void scan_kernel(
    const float* __restrict__ A_log, const float* __restrict__ dt_t,
    const float* __restrict__ dtu_t, const float* __restrict__ Bm,
    const float* __restrict__ Cm_t, float* __restrict__ part) {
  // XCD-aware remap (kept from v12): xcd = bid&7 owns contiguous sids.
  const int bid = blockIdx.x;        // 0..4607
  const int xcd = bid & 7;
  const int slot = bid >> 3;         // 0..575 within this XCD
  const int sid = xcd * 96 + slot / 6;
  const int w = slot % 6;            // j-split
  const int lane = threadIdx.x;      // 0..63
  const int b = sid / D_SZ;
  const int i = sid % D_SZ;
  const int j = w * 64 + lane;

  const float a2 = -__expf(A_log[i * S_SZ + j]) * LOG2E;
  const float bw = Bm[(b * D_SZ + i) * S_SZ + j];
  float h = 0.f;

  const float* dtB = dt_t + (b * D_SZ + i) * L_SZ;   // uniform, contiguous l
  const float* duB = dtu_t + (b * D_SZ + i) * L_SZ;
  const float* cmt = Cm_t + (b * S_SZ + j) * L_SZ;   // per-lane row, contiguous l

  // fold result mapping: lane r holds value s = (b3<<2)|(b2<<1)|b0 of chunk;
  // lanes with bits {1,4,5} == 0 store (8 lanes cover s=0..7).
  const int sq = (((lane >> 3) & 1) << 2) | (((lane >> 2) & 1) << 1) | (lane & 1);
  const bool storer = (lane & 0x32) == 0;
  float* pstore = part + ((w * B_SZ + b) * D_SZ + i) * L_SZ + sq;

  // drain initial compiler loads so vmcnt counting is exact
  asm volatile("" :: "v"(a2), "v"(bw));
  asm volatile("s_waitcnt vmcnt(0)");

  auto compute_chunk = [&](ChunkS& K) {
    float acc[8];
    const float dts[8] = {K.d0[0], K.d0[1], K.d0[2], K.d0[3],
                          K.d1[0], K.d1[1], K.d1[2], K.d1[3]};
    const float dus[8] = {K.u0[0], K.u0[1], K.u0[2], K.u0[3],
                          K.u1[0], K.u1[1], K.u1[2], K.u1[3]};
    const float cs[8] = {K.c0[0], K.c0[1], K.c0[2], K.c0[3],
                         K.c1[0], K.c1[1], K.c1[2], K.c1[3]};
#pragma unroll
    for (int s = 0; s < 8; ++s) {
      const float e = fexp2(dts[s] * a2);
      h = fmaf(e, h, bw * dus[s]);
      acc[s] = h * cs[s];
    }
    // fold stage 1: pairing xor15 (row_mirror), side bit3, n2=4
    {
      const bool hi = (lane & 8) != 0;
#pragma unroll
      for (int q = 0; q < 4; ++q) {
        const float keep = hi ? acc[q + 4] : acc[q];
        const float send = hi ? acc[q] : acc[q + 4];
        acc[q] = keep + dpp_mov<0x140>(send);
      }
    }
    // fold stage 2: pairing xor7 (row_half_mirror), side bit2, n2=2
    {
      const bool hi = (lane & 4) != 0;
#pragma unroll
      for (int q = 0; q < 2; ++q) {
        const float keep = hi ? acc[q + 2] : acc[q];
        const float send = hi ? acc[q] : acc[q + 2];
        acc[q] = keep + dpp_mov<0x141>(send);
      }
    }
    // fold stage 3: pairing xor1 (quad_perm [1,0,3,2]), side bit0, n2=1
    {
      const bool hi = (lane & 1) != 0;
      const float keep = hi ? acc[1] : acc[0];
      const float send = hi ? acc[0] : acc[1];
      acc[0] = keep + dpp_mov<0xB1>(send);
    }
    // finish across unused bits {1,4,5}: all VALU-pipe lane exchanges
    float r = acc[0];
    r += dpp_mov<0x4E>(r);   // xor2: quad_perm [2,3,0,1]
    r = fold_xor16(r);       // xor16: permlane16_swap builtin
    r = fold_xor32(r);       // xor32: permlane32_swap builtin
    if (storer) *pstore = r;
    pstore += 8;
  };

  ChunkS K0, K1, K2;
  LOAD_CHUNK(K0, cmt, dtB, duB);
  ADV_BASES();
  LOAD_CHUNK(K1, cmt, dtB, duB);
  ADV_BASES();
#pragma unroll 1
  for (int it = 0; it < 16; ++it) {
    LOAD_CHUNK(K2, cmt, dtB, duB);
    ADV_BASES();
    WAIT_CHUNK(K0);
    compute_chunk(K0);
    LOAD_CHUNK(K0, cmt, dtB, duB);
    ADV_BASES();
    WAIT_CHUNK(K1);
    compute_chunk(K1);
    LOAD_CHUNK(K1, cmt, dtB, duB);
    ADV_BASES();
    WAIT_CHUNK(K2);
    compute_chunk(K2);
  }
  // 48 chunks computed; the 2 extra prefetched chunks are never waited on
  // and read harmlessly into the adjacent workspace slots.
}

// ---------------------------------------------------------------------------
// Combine + transpose: y[b,l,i] = sum_{w<6} part[w][b][i][l] + u[b,l,i]*D[i]
// ---------------------------------------------------------------------------
__global__ __launch_bounds__(256) void combine_kernel(
    const float* __restrict__ part, const float* __restrict__ u,
    const float* __restrict__ Dv, float* __restrict__ y) {
  __shared__ float T[32][33];
  const int tx = threadIdx.x;
  const int ty0 = threadIdx.y;
  const int b = blockIdx.z;
  const int i0 = blockIdx.y * 32;
  const int l0 = blockIdx.x * 32;
#pragma unroll
  for (int r = 0; r < 4; ++r) {
    const int il = ty0 + 8 * r;
    float s = 0.f;
#pragma unroll
    for (int w = 0; w < 6; ++w)
      s += part[((w * B_SZ + b) * D_SZ + i0 + il) * L_SZ + l0 + tx];
    T[il][tx] = s;
  }
  __syncthreads();
#pragma unroll
  for (int r = 0; r < 4; ++r) {
    const int ll = ty0 + 8 * r;
    const int gi = i0 + tx;
    const int off = (b * L_SZ + l0 + ll) * D_SZ + gi;
    y[off] = fmaf(u[off], Dv[gi], T[tx][ll]);
  }
}

extern "C" void kernel_launch(void* const* d_in, const int* in_sizes, int n_in,
                              void* d_out, int out_size, void* d_ws,
                              size_t ws_size, hipStream_t stream) {
  const float* x = (const float*)d_in[0];
  const float* A_log = (const float*)d_in[1];
  const float* D = (const float*)d_in[2];
  const float* dt_w = (const float*)d_in[3];
  const float* dt_b = (const float*)d_in[4];
  const float* B_w = (const float*)d_in[5];
  const float* C_w = (const float*)d_in[6];
  const float* conv_w = (const float*)d_in[7];
  const float* conv_b = (const float*)d_in[8];
  float* y = (float*)d_out;

  float* ws = (float*)d_ws;
  float* dt = ws;                     // slot 0  [b,l,i]
  float* u = ws + TOT_ELEMS;          // slot 1
  float* Bm = ws + 2 * TOT_ELEMS;     // slot 2
  float* Cm = ws + 3 * TOT_ELEMS;     // slot 3  [b,l,s]
  float* dt_t = ws + 4 * TOT_ELEMS;   // slot 4  [b,i,l]
  float* dtu_t = ws + 5 * TOT_ELEMS;  // slot 5  [b,i,l]
  float* part = ws + 6 * TOT_ELEMS;   // slots 6..11  [w][b][i][l], w<6
  float* Cm_t = ws + 12 * TOT_ELEMS;  // slot 12 [b,s,l]
  unsigned short* xdblbf = (unsigned short*)(ws + 13 * TOT_ELEMS);  // 294912

  mfma_dual_gemm<1><<<dim3(24, 24), 128, 0, stream>>>(x, dt_w, B_w, dt_b, dt, xdblbf);
  mfma_dual_gemm<2><<<dim3(24, 24), 128, 0, stream>>>(xdblbf, B_w, C_w, nullptr, Bm, Cm);
  conv_tr_kernel<<<dim3(L_SZ / 32, D_SZ / 32, B_SZ), dim3(32, 8), 0, stream>>>(
      x, conv_w, conv_b, dt, Cm, u, dt_t, dtu_t, Cm_t);
  scan_kernel<<<4608, 64, 0, stream>>>(A_log, dt_t, dtu_t, Bm, Cm_t, part);
  combine_kernel<<<dim3(L_SZ / 32, D_SZ / 32, B_SZ), dim3(32, 8), 0, stream>>>(
      part, u, D, y);
}

// Round 7
// 145.260 us; speedup vs baseline: 1.1859x; 1.1859x over previous
//
#include <hip/hip_runtime.h>
#include <math.h>

// Dims (fixed by the problem)
#define B_SZ 2
#define L_SZ 384
#define D_SZ 384
#define S_SZ 384
#define BLK_ELEMS (L_SZ * D_SZ)        // 147456 per batch
#define TOT_ELEMS (B_SZ * L_SZ * D_SZ) // 294912
#define LOG2E 1.4426950408889634f

typedef __attribute__((ext_vector_type(8))) short bf16x8;
typedef __attribute__((ext_vector_type(4))) float f32x4;
typedef __attribute__((ext_vector_type(2))) unsigned int u32x2;

__device__ __forceinline__ float fexp2(float x) {
  return __builtin_amdgcn_exp2f(x);
}
__device__ __forceinline__ float softplus_f(float z) {
  return (z > 20.f) ? z : log1pf(__expf(z));
}
__device__ __forceinline__ unsigned short f2bf(float f) {  // RNE f32->bf16
  unsigned int u = __float_as_uint(f);
  return (unsigned short)((u + 0x7FFFu + ((u >> 16) & 1u)) >> 16);
}
#define PIPELINE_FENCE() asm volatile("" ::: "memory")

// 8x f32 -> 8x bf16 (RNE) via v_cvt_pk_bf16_f32 (plain VALU asm — no
// hazard class, unlike permlane).
__device__ __forceinline__ bf16x8 cvt8(const float* p) {
  const f32x4 v0 = *(const f32x4*)p;
  const f32x4 v1 = *(const f32x4*)(p + 4);
  union { unsigned int u[4]; bf16x8 v; } r;
  asm("v_cvt_pk_bf16_f32 %0, %1, %2" : "=v"(r.u[0]) : "v"(v0[0]), "v"(v0[1]));
  asm("v_cvt_pk_bf16_f32 %0, %1, %2" : "=v"(r.u[1]) : "v"(v0[2]), "v"(v0[3]));
  asm("v_cvt_pk_bf16_f32 %0, %1, %2" : "=v"(r.u[2]) : "v"(v1[0]), "v"(v1[1]));
  asm("v_cvt_pk_bf16_f32 %0, %1, %2" : "=v"(r.u[3]) : "v"(v1[2]), "v"(v1[3]));
  return r.v;
}

// DPP lane exchange (VALU pipe). CTRL: 0x140=row_mirror (xor15),
// 0x141=row_half_mirror (xor7), 0xB1=quad_perm[1,0,3,2] (xor1),
// 0x4E=quad_perm[2,3,0,1] (xor2).
template <int CTRL>
__device__ __forceinline__ float dpp_mov(float v) {
  return __int_as_float(
      __builtin_amdgcn_update_dpp(0, __float_as_int(v), CTRL, 0xF, 0xF, true));
}

// r + shfl_xor(r,16)/(r,32) in ALL lanes via permlane*_swap BUILTINS
// (raw asm hit the gfx950 VALU-write->permlane wait-state hazard, v13).
__device__ __forceinline__ float fold_xor16(float r) {
#if __has_builtin(__builtin_amdgcn_permlane16_swap)
  const unsigned ru = __float_as_uint(r);
  u32x2 p = __builtin_amdgcn_permlane16_swap(ru, ru, false, false);
  return __uint_as_float(p[0]) + __uint_as_float(p[1]);
#else
  return r + __shfl_xor(r, 16, 64);
#endif
}
__device__ __forceinline__ float fold_xor32(float r) {
#if __has_builtin(__builtin_amdgcn_permlane32_swap)
  const unsigned ru = __float_as_uint(r);
  u32x2 p = __builtin_amdgcn_permlane32_swap(ru, ru, false, false);
  return __uint_as_float(p[0]) + __uint_as_float(p[1]);
#else
  return r + __shfl_xor(r, 32, 64);
#endif
}

// ---------------------------------------------------------------------------
// LDS-staged dual MFMA NT-GEMM. MODE 1: A is f32 (x), epilogue softplus+bf16.
// MODE 2: A is bf16 (xdbl), epilogue f32+f32. W1/W2 f32, converted in
// staging (cvt fused; separate cvt kernel deleted — measured neutral).
// ---------------------------------------------------------------------------
template <int MODE>
__global__ __launch_bounds__(128, 2) void mfma_dual_gemm(
    const void* __restrict__ Av, const float* __restrict__ W1,
    const float* __restrict__ W2, const float* __restrict__ bias,
    float* __restrict__ O1, void* __restrict__ O2v) {
  __shared__ unsigned short sA[32 * 392];
  __shared__ unsigned short sW1[16 * 392];
  __shared__ unsigned short sW2[16 * 392];

  const int t = threadIdx.x;
  const int wv = t >> 6;
  const int lane = t & 63;
  const int nt = blockIdx.x;
  const int mrow = blockIdx.y;

  const float* W1b = W1 + nt * 16 * 384;
  const float* W2b = W2 + nt * 16 * 384;

  if constexpr (MODE == 1) {
    const float* Ab = (const float*)Av + mrow * 32 * 384;
#pragma unroll
    for (int it = 0; it < 12; ++it) {
      const int id = t + it * 128;
      const int row = id / 48, col = id - row * 48;
      *(bf16x8*)&sA[row * 392 + col * 8] = cvt8(Ab + id * 8);
    }
  } else {
    const unsigned short* Ab = (const unsigned short*)Av + mrow * 32 * 384;
#pragma unroll
    for (int it = 0; it < 12; ++it) {
      const int id = t + it * 128;
      const int row = id / 48, col = id - row * 48;
      *(bf16x8*)&sA[row * 392 + col * 8] = *(const bf16x8*)(Ab + id * 8);
    }
  }
#pragma unroll
  for (int it = 0; it < 6; ++it) {
    const int id = t + it * 128;
    const int row = id / 48, col = id - row * 48;
    *(bf16x8*)&sW1[row * 392 + col * 8] = cvt8(W1b + id * 8);
    *(bf16x8*)&sW2[row * 392 + col * 8] = cvt8(W2b + id * 8);
  }
  __syncthreads();

  const int rc = lane & 15;
  const int quad = lane >> 4;
  bf16x8 af[12], w1f[12], w2f[12];
#pragma unroll
  for (int kt = 0; kt < 12; ++kt) {
    af[kt] = *(const bf16x8*)&sA[(wv * 16 + rc) * 392 + quad * 8 + kt * 32];
    w1f[kt] = *(const bf16x8*)&sW1[rc * 392 + quad * 8 + kt * 32];
    w2f[kt] = *(const bf16x8*)&sW2[rc * 392 + quad * 8 + kt * 32];
  }
  PIPELINE_FENCE();
  f32x4 acc1 = {0.f, 0.f, 0.f, 0.f};
  f32x4 acc2 = {0.f, 0.f, 0.f, 0.f};
#pragma unroll
  for (int kt = 0; kt < 12; ++kt) {
    acc1 = __builtin_amdgcn_mfma_f32_16x16x32_bf16(af[kt], w1f[kt], acc1, 0, 0, 0);
    acc2 = __builtin_amdgcn_mfma_f32_16x16x32_bf16(af[kt], w2f[kt], acc2, 0, 0, 0);
  }
  const int col = nt * 16 + rc;
  const int row0 = mrow * 32 + wv * 16 + quad * 4;
  if constexpr (MODE == 1) {
    unsigned short* O2 = (unsigned short*)O2v;
    const float bb = bias[col];
#pragma unroll
    for (int r = 0; r < 4; ++r) {
      O1[(row0 + r) * 384 + col] = softplus_f(acc1[r] + bb);
      O2[(row0 + r) * 384 + col] = f2bf(acc2[r]);
    }
  } else {
    float* O2 = (float*)O2v;
#pragma unroll
    for (int r = 0; r < 4; ++r) {
      O1[(row0 + r) * 384 + col] = acc1[r];
      O2[(row0 + r) * 384 + col] = acc2[r];
    }
  }
}

// ---------------------------------------------------------------------------
// Conv + SiLU + transpose (R4 version).
// ---------------------------------------------------------------------------
__global__ __launch_bounds__(256) void conv_tr_kernel(
    const float* __restrict__ x, const float* __restrict__ cw,
    const float* __restrict__ cb, const float* __restrict__ dt,
    float* __restrict__ u, float* __restrict__ dt_t,
    float* __restrict__ dtu_t) {
  __shared__ float Tdt[32][33];
  __shared__ float Tdu[32][33];
  const int tx = threadIdx.x;
  const int ty = threadIdx.y;
  const int b = blockIdx.z;
  const int i0 = blockIdx.y * 32;
  const int l0 = blockIdx.x * 32;
  const int gi = i0 + tx;
  const float cbv = cb[gi];
  const float cw0 = cw[gi * 4 + 0], cw1 = cw[gi * 4 + 1];
  const float cw2 = cw[gi * 4 + 2], cw3 = cw[gi * 4 + 3];
#pragma unroll
  for (int r = 0; r < 4; ++r) {
    const int l = l0 + ty + 8 * r;
    float acc = cbv;
    const float x3 = x[(b * L_SZ + l) * D_SZ + gi];
    const float x2 = (l >= 1) ? x[(b * L_SZ + l - 1) * D_SZ + gi] : 0.f;
    const float x1 = (l >= 2) ? x[(b * L_SZ + l - 2) * D_SZ + gi] : 0.f;
    const float x0 = (l >= 3) ? x[(b * L_SZ + l - 3) * D_SZ + gi] : 0.f;
    acc = fmaf(x0, cw0, acc);
    acc = fmaf(x1, cw1, acc);
    acc = fmaf(x2, cw2, acc);
    acc = fmaf(x3, cw3, acc);
    const float uv = acc / (1.f + __expf(-acc));
    const int off = (b * L_SZ + l) * D_SZ + gi;
    u[off] = uv;
    const float dtv = dt[off];
    Tdt[ty + 8 * r][tx] = dtv;
    Tdu[ty + 8 * r][tx] = dtv * uv;
  }
  __syncthreads();
#pragma unroll
  for (int r = 0; r < 4; ++r) {
    const int il = ty + 8 * r;
    const int off = (b * D_SZ + i0 + il) * L_SZ + l0 + tx;
    dt_t[off] = Tdt[tx][il];
    dtu_t[off] = Tdu[tx][il];
  }
}

// ---------------------------------------------------------------------------
// Selective scan v17 = v16 (fused combine) with the dangling-prefetch bug
// fixed. v16 crashed (GPU memory fault): the 2 never-waited prefetched
// chunks left global_load_dwordx4s in flight past the loop; the register
// allocator reused K0/K1's VGPRs for the combine's address math, and the
// returning loads clobbered them -> wild store. v11-v14 got away with it
// because the kernel ended right after the loop (clobbered regs dead).
// Fix: exactly 48 loads / 48 waits — 15 main iterations + epilogue that
// drains vmcnt 24 -> 12 -> 0 before __syncthreads. No outstanding VMEM at
// the combine, and no past-end reads at all.
// ---------------------------------------------------------------------------
struct ChunkS {
  f32x4 d0, d1, u0, u1;
  float c[8];
};

#define LOAD_CHUNK(K, B0, B1, B2, DTB, DUB)                                    \
  {                                                                            \
    asm volatile("global_load_dwordx4 %0, %1, off" : "=v"(K.d0) : "v"(DTB));   \
    asm volatile("global_load_dwordx4 %0, %1, off offset:16"                   \
                 : "=v"(K.d1) : "v"(DTB));                                     \
    asm volatile("global_load_dwordx4 %0, %1, off" : "=v"(K.u0) : "v"(DUB));   \
    asm volatile("global_load_dwordx4 %0, %1, off offset:16"                   \
                 : "=v"(K.u1) : "v"(DUB));                                     \
    asm volatile("global_load_dword %0, %1, off" : "=v"(K.c[0]) : "v"(B0));    \
    asm volatile("global_load_dword %0, %1, off offset:1536"                   \
                 : "=v"(K.c[1]) : "v"(B0));                                    \
    asm volatile("global_load_dword %0, %1, off offset:3072"                   \
                 : "=v"(K.c[2]) : "v"(B0));                                    \
    asm volatile("global_load_dword %0, %1, off" : "=v"(K.c[3]) : "v"(B1));    \
    asm volatile("global_load_dword %0, %1, off offset:1536"                   \
                 : "=v"(K.c[4]) : "v"(B1));                                    \
    asm volatile("global_load_dword %0, %1, off offset:3072"                   \
                 : "=v"(K.c[5]) : "v"(B1));                                    \
    asm volatile("global_load_dword %0, %1, off" : "=v"(K.c[6]) : "v"(B2));    \
    asm volatile("global_load_dword %0, %1, off offset:1536"                   \
                 : "=v"(K.c[7]) : "v"(B2));                                    \
  }

#define WAIT_CHUNK_IMM(K, S)                                                   \
  asm volatile("s_waitcnt vmcnt(" S ")"                                        \
               : "+v"(K.d0), "+v"(K.d1), "+v"(K.u0), "+v"(K.u1),               \
                 "+v"(K.c[0]), "+v"(K.c[1]), "+v"(K.c[2]), "+v"(K.c[3]),       \
                 "+v"(K.c[4]), "+v"(K.c[5]), "+v"(K.c[6]), "+v"(K.c[7]))

#define ADV_BASES()                                                            \
  { cb0 += 3072; cb1 += 3072; cb2 += 3072; dtB += 8; duB += 8; }

__global__ __launch_bounds__(384, 4) void scan_kernel(
    const float* __restrict__ A_log, const float* __restrict__ dt_t,
    const float* __restrict__ dtu_t, const float* __restrict__ Bm,
    const float* __restrict__ Cm, const float* __restrict__ u,
    const float* __restrict__ Dv, float* __restrict__ y) {
  __shared__ float sP[6 * L_SZ];      // per-wave folded partials [w][l]
  const int bid = blockIdx.x;         // 0..767 (one block per sid)
  const int xcd = bid & 7;
  const int sid = xcd * 96 + (bid >> 3);  // XCD-contiguous sids (kept)
  const int w = threadIdx.x >> 6;     // j-split wave 0..5
  const int lane = threadIdx.x & 63;
  const int b = sid / D_SZ;
  const int i = sid % D_SZ;
  const int j = w * 64 + lane;

  const float a2 = -__expf(A_log[i * S_SZ + j]) * LOG2E;
  const float bw = Bm[(b * D_SZ + i) * S_SZ + j];
  float h = 0.f;

  const float* dtB = dt_t + (b * D_SZ + i) * L_SZ;   // uniform, contiguous l
  const float* duB = dtu_t + (b * D_SZ + i) * L_SZ;
  // Cm row bases (rows 0..2, 3..5, 6..7 of each chunk via imm 0/1536/3072)
  const float* cmrow = Cm + b * BLK_ELEMS + j;
  const float* cb0 = cmrow;
  const float* cb1 = cmrow + 3 * D_SZ;
  const float* cb2 = cmrow + 6 * D_SZ;

  // fold result mapping: lane r holds value s = (b3<<2)|(b2<<1)|b0 of chunk;
  // lanes with bits {1,4,5} == 0 store (8 lanes cover s=0..7).
  const int sq = (((lane >> 3) & 1) << 2) | (((lane >> 2) & 1) << 1) | (lane & 1);
  const bool storer = (lane & 0x32) == 0;
  int pidx = w * L_SZ + sq;           // LDS partial index (advances +8/chunk)

  // drain initial compiler loads so vmcnt counting is exact
  asm volatile("" :: "v"(a2), "v"(bw));
  asm volatile("s_waitcnt vmcnt(0)");

  auto compute_chunk = [&](ChunkS& K) {
    float acc[8];
    const float dts[8] = {K.d0[0], K.d0[1], K.d0[2], K.d0[3],
                          K.d1[0], K.d1[1], K.d1[2], K.d1[3]};
    const float dus[8] = {K.u0[0], K.u0[1], K.u0[2], K.u0[3],
                          K.u1[0], K.u1[1], K.u1[2], K.u1[3]};
#pragma unroll
    for (int s = 0; s < 8; ++s) {
      const float e = fexp2(dts[s] * a2);
      h = fmaf(e, h, bw * dus[s]);
      acc[s] = h * K.c[s];
    }
    // fold stage 1: pairing xor15 (row_mirror), side bit3, n2=4
    {
      const bool hi = (lane & 8) != 0;
#pragma unroll
      for (int q = 0; q < 4; ++q) {
        const float keep = hi ? acc[q + 4] : acc[q];
        const float send = hi ? acc[q] : acc[q + 4];
        acc[q] = keep + dpp_mov<0x140>(send);
      }
    }
    // fold stage 2: pairing xor7 (row_half_mirror), side bit2, n2=2
    {
      const bool hi = (lane & 4) != 0;
#pragma unroll
      for (int q = 0; q < 2; ++q) {
        const float keep = hi ? acc[q + 2] : acc[q];
        const float send = hi ? acc[q] : acc[q + 2];
        acc[q] = keep + dpp_mov<0x141>(send);
      }
    }
    // fold stage 3: pairing xor1 (quad_perm [1,0,3,2]), side bit0, n2=1
    {
      const bool hi = (lane & 1) != 0;
      const float keep = hi ? acc[1] : acc[0];
      const float send = hi ? acc[0] : acc[1];
      acc[0] = keep + dpp_mov<0xB1>(send);
    }
    // finish across unused bits {1,4,5}: all VALU-pipe lane exchanges
    float r = acc[0];
    r += dpp_mov<0x4E>(r);   // xor2: quad_perm [2,3,0,1]
    r = fold_xor16(r);       // xor16: permlane16_swap builtin
    r = fold_xor32(r);       // xor32: permlane32_swap builtin
    if (storer) sP[pidx] = r;  // LDS store (lgkmcnt — vmcnt stays exact)
    pidx += 8;
  };

  ChunkS K0, K1, K2;
  LOAD_CHUNK(K0, cb0, cb1, cb2, dtB, duB);   // c0
  ADV_BASES();
  LOAD_CHUNK(K1, cb0, cb1, cb2, dtB, duB);   // c1
  ADV_BASES();
#pragma unroll 1
  for (int it = 0; it < 15; ++it) {          // computes c0..c44
    LOAD_CHUNK(K2, cb0, cb1, cb2, dtB, duB);
    ADV_BASES();
    WAIT_CHUNK_IMM(K0, "24");
    compute_chunk(K0);
    LOAD_CHUNK(K0, cb0, cb1, cb2, dtB, duB);
    ADV_BASES();
    WAIT_CHUNK_IMM(K1, "24");
    compute_chunk(K1);
    LOAD_CHUNK(K1, cb0, cb1, cb2, dtB, duB);
    ADV_BASES();
    WAIT_CHUNK_IMM(K2, "24");
    compute_chunk(K2);
  }
  // pending: K0=c45, K1=c46. Load the last chunk and drain fully.
  LOAD_CHUNK(K2, cb0, cb1, cb2, dtB, duB);   // c47
  WAIT_CHUNK_IMM(K0, "24");
  compute_chunk(K0);                         // c45
  WAIT_CHUNK_IMM(K1, "12");
  compute_chunk(K1);                         // c46
  WAIT_CHUNK_IMM(K2, "0");
  compute_chunk(K2);                         // c47 — vmcnt now 0

  // Fused combine: y[b,l,i] = sum_w sP[w][l] + u[b,l,i]*D[i]
  __syncthreads();
  const int l = threadIdx.x;          // 0..383
  const float s6 = sP[l] + sP[L_SZ + l] + sP[2 * L_SZ + l] +
                   sP[3 * L_SZ + l] + sP[4 * L_SZ + l] + sP[5 * L_SZ + l];
  const int off = (b * L_SZ + l) * D_SZ + i;
  y[off] = fmaf(u[off], Dv[i], s6);
}

extern "C" void kernel_launch(void* const* d_in, const int* in_sizes, int n_in,
                              void* d_out, int out_size, void* d_ws,
                              size_t ws_size, hipStream_t stream) {
  const float* x = (const float*)d_in[0];
  const float* A_log = (const float*)d_in[1];
  const float* D = (const float*)d_in[2];
  const float* dt_w = (const float*)d_in[3];
  const float* dt_b = (const float*)d_in[4];
  const float* B_w = (const float*)d_in[5];
  const float* C_w = (const float*)d_in[6];
  const float* conv_w = (const float*)d_in[7];
  const float* conv_b = (const float*)d_in[8];
  float* y = (float*)d_out;

  float* ws = (float*)d_ws;
  float* dt = ws;                     // slot 0  [b,l,i]
  float* u = ws + TOT_ELEMS;          // slot 1
  float* Bm = ws + 2 * TOT_ELEMS;     // slot 2
  float* Cm = ws + 3 * TOT_ELEMS;     // slot 3  [b,l,s]
  float* dt_t = ws + 4 * TOT_ELEMS;   // slot 4  [b,i,l]
  float* dtu_t = ws + 5 * TOT_ELEMS;  // slot 5  [b,i,l]
  unsigned short* xdblbf = (unsigned short*)(ws + 6 * TOT_ELEMS);  // 294912

  mfma_dual_gemm<1><<<dim3(24, 24), 128, 0, stream>>>(x, dt_w, B_w, dt_b, dt, xdblbf);
  mfma_dual_gemm<2><<<dim3(24, 24), 128, 0, stream>>>(xdblbf, B_w, C_w, nullptr, Bm, Cm);
  conv_tr_kernel<<<dim3(L_SZ / 32, D_SZ / 32, B_SZ), dim3(32, 8), 0, stream>>>(
      x, conv_w, conv_b, dt, u, dt_t, dtu_t);
  scan_kernel<<<768, 384, 0, stream>>>(A_log, dt_t, dtu_t, Bm, Cm, u, D, y);
}

// Round 8
// 137.321 us; speedup vs baseline: 1.2544x; 1.0578x over previous
//
#include <hip/hip_runtime.h>
#include <math.h>

// Dims (fixed by the problem)
#define B_SZ 2
#define L_SZ 384
#define D_SZ 384
#define S_SZ 384
#define BLK_ELEMS (L_SZ * D_SZ)        // 147456 per batch
#define TOT_ELEMS (B_SZ * L_SZ * D_SZ) // 294912
#define LOG2E 1.4426950408889634f

typedef __attribute__((ext_vector_type(8))) short bf16x8;
typedef __attribute__((ext_vector_type(4))) float f32x4;
typedef __attribute__((ext_vector_type(2))) unsigned int u32x2;

__device__ __forceinline__ float fexp2(float x) {
  return __builtin_amdgcn_exp2f(x);
}
__device__ __forceinline__ float softplus_f(float z) {
  return (z > 20.f) ? z : log1pf(__expf(z));
}
__device__ __forceinline__ unsigned short f2bf(float f) {  // RNE f32->bf16
  unsigned int u = __float_as_uint(f);
  return (unsigned short)((u + 0x7FFFu + ((u >> 16) & 1u)) >> 16);
}
#define PIPELINE_FENCE() asm volatile("" ::: "memory")

// 8x f32 -> 8x bf16 (RNE) via v_cvt_pk_bf16_f32 (plain VALU asm — no
// hazard class, unlike permlane).
__device__ __forceinline__ bf16x8 cvt8(const float* p) {
  const f32x4 v0 = *(const f32x4*)p;
  const f32x4 v1 = *(const f32x4*)(p + 4);
  union { unsigned int u[4]; bf16x8 v; } r;
  asm("v_cvt_pk_bf16_f32 %0, %1, %2" : "=v"(r.u[0]) : "v"(v0[0]), "v"(v0[1]));
  asm("v_cvt_pk_bf16_f32 %0, %1, %2" : "=v"(r.u[1]) : "v"(v0[2]), "v"(v0[3]));
  asm("v_cvt_pk_bf16_f32 %0, %1, %2" : "=v"(r.u[2]) : "v"(v1[0]), "v"(v1[1]));
  asm("v_cvt_pk_bf16_f32 %0, %1, %2" : "=v"(r.u[3]) : "v"(v1[2]), "v"(v1[3]));
  return r.v;
}

// DPP lane exchange (VALU pipe). CTRL: 0x140=row_mirror (xor15),
// 0x141=row_half_mirror (xor7), 0xB1=quad_perm[1,0,3,2] (xor1),
// 0x4E=quad_perm[2,3,0,1] (xor2).
template <int CTRL>
__device__ __forceinline__ float dpp_mov(float v) {
  return __int_as_float(
      __builtin_amdgcn_update_dpp(0, __float_as_int(v), CTRL, 0xF, 0xF, true));
}

// r + shfl_xor(r,16)/(r,32) in ALL lanes via permlane*_swap BUILTINS
// (raw asm hit the gfx950 VALU-write->permlane wait-state hazard, v13).
__device__ __forceinline__ float fold_xor16(float r) {
#if __has_builtin(__builtin_amdgcn_permlane16_swap)
  const unsigned ru = __float_as_uint(r);
  u32x2 p = __builtin_amdgcn_permlane16_swap(ru, ru, false, false);
  return __uint_as_float(p[0]) + __uint_as_float(p[1]);
#else
  return r + __shfl_xor(r, 16, 64);
#endif
}
__device__ __forceinline__ float fold_xor32(float r) {
#if __has_builtin(__builtin_amdgcn_permlane32_swap)
  const unsigned ru = __float_as_uint(r);
  u32x2 p = __builtin_amdgcn_permlane32_swap(ru, ru, false, false);
  return __uint_as_float(p[0]) + __uint_as_float(p[1]);
#else
  return r + __shfl_xor(r, 32, 64);
#endif
}

// ---------------------------------------------------------------------------
// LDS-staged dual MFMA NT-GEMM. MODE 1: A=f32 (x), O1=softplus dt (f32),
// O2=xdbl bf16. MODE 2: A=bf16 (xdbl), O1=Bm f32, O2=Cm bf16 (NEW: the
// scan streams Cm as ushort loads — halves its L2 line-request rate).
// ---------------------------------------------------------------------------
template <int MODE>
__global__ __launch_bounds__(128, 2) void mfma_dual_gemm(
    const void* __restrict__ Av, const float* __restrict__ W1,
    const float* __restrict__ W2, const float* __restrict__ bias,
    float* __restrict__ O1, unsigned short* __restrict__ O2) {
  __shared__ unsigned short sA[32 * 392];
  __shared__ unsigned short sW1[16 * 392];
  __shared__ unsigned short sW2[16 * 392];

  const int t = threadIdx.x;
  const int wv = t >> 6;
  const int lane = t & 63;
  const int nt = blockIdx.x;
  const int mrow = blockIdx.y;

  const float* W1b = W1 + nt * 16 * 384;
  const float* W2b = W2 + nt * 16 * 384;

  if constexpr (MODE == 1) {
    const float* Ab = (const float*)Av + mrow * 32 * 384;
#pragma unroll
    for (int it = 0; it < 12; ++it) {
      const int id = t + it * 128;
      const int row = id / 48, col = id - row * 48;
      *(bf16x8*)&sA[row * 392 + col * 8] = cvt8(Ab + id * 8);
    }
  } else {
    const unsigned short* Ab = (const unsigned short*)Av + mrow * 32 * 384;
#pragma unroll
    for (int it = 0; it < 12; ++it) {
      const int id = t + it * 128;
      const int row = id / 48, col = id - row * 48;
      *(bf16x8*)&sA[row * 392 + col * 8] = *(const bf16x8*)(Ab + id * 8);
    }
  }
#pragma unroll
  for (int it = 0; it < 6; ++it) {
    const int id = t + it * 128;
    const int row = id / 48, col = id - row * 48;
    *(bf16x8*)&sW1[row * 392 + col * 8] = cvt8(W1b + id * 8);
    *(bf16x8*)&sW2[row * 392 + col * 8] = cvt8(W2b + id * 8);
  }
  __syncthreads();

  const int rc = lane & 15;
  const int quad = lane >> 4;
  bf16x8 af[12], w1f[12], w2f[12];
#pragma unroll
  for (int kt = 0; kt < 12; ++kt) {
    af[kt] = *(const bf16x8*)&sA[(wv * 16 + rc) * 392 + quad * 8 + kt * 32];
    w1f[kt] = *(const bf16x8*)&sW1[rc * 392 + quad * 8 + kt * 32];
    w2f[kt] = *(const bf16x8*)&sW2[rc * 392 + quad * 8 + kt * 32];
  }
  PIPELINE_FENCE();
  f32x4 acc1 = {0.f, 0.f, 0.f, 0.f};
  f32x4 acc2 = {0.f, 0.f, 0.f, 0.f};
#pragma unroll
  for (int kt = 0; kt < 12; ++kt) {
    acc1 = __builtin_amdgcn_mfma_f32_16x16x32_bf16(af[kt], w1f[kt], acc1, 0, 0, 0);
    acc2 = __builtin_amdgcn_mfma_f32_16x16x32_bf16(af[kt], w2f[kt], acc2, 0, 0, 0);
  }
  const int col = nt * 16 + rc;
  const int row0 = mrow * 32 + wv * 16 + quad * 4;
  if constexpr (MODE == 1) {
    const float bb = bias[col];
#pragma unroll
    for (int r = 0; r < 4; ++r) {
      O1[(row0 + r) * 384 + col] = softplus_f(acc1[r] + bb);
      O2[(row0 + r) * 384 + col] = f2bf(acc2[r]);
    }
  } else {
#pragma unroll
    for (int r = 0; r < 4; ++r) {
      O1[(row0 + r) * 384 + col] = acc1[r];
      O2[(row0 + r) * 384 + col] = f2bf(acc2[r]);
    }
  }
}

// ---------------------------------------------------------------------------
// Conv + SiLU + transpose (R2-proven version, unchanged).
// ---------------------------------------------------------------------------
__global__ __launch_bounds__(256) void conv_tr_kernel(
    const float* __restrict__ x, const float* __restrict__ cw,
    const float* __restrict__ cb, const float* __restrict__ dt,
    float* __restrict__ u, float* __restrict__ dt_t,
    float* __restrict__ dtu_t) {
  __shared__ float Tdt[32][33];
  __shared__ float Tdu[32][33];
  const int tx = threadIdx.x;
  const int ty = threadIdx.y;
  const int b = blockIdx.z;
  const int i0 = blockIdx.y * 32;
  const int l0 = blockIdx.x * 32;
  const int gi = i0 + tx;
  const float cbv = cb[gi];
  const float cw0 = cw[gi * 4 + 0], cw1 = cw[gi * 4 + 1];
  const float cw2 = cw[gi * 4 + 2], cw3 = cw[gi * 4 + 3];
#pragma unroll
  for (int r = 0; r < 4; ++r) {
    const int l = l0 + ty + 8 * r;
    float acc = cbv;
    const float x3 = x[(b * L_SZ + l) * D_SZ + gi];
    const float x2 = (l >= 1) ? x[(b * L_SZ + l - 1) * D_SZ + gi] : 0.f;
    const float x1 = (l >= 2) ? x[(b * L_SZ + l - 2) * D_SZ + gi] : 0.f;
    const float x0 = (l >= 3) ? x[(b * L_SZ + l - 3) * D_SZ + gi] : 0.f;
    acc = fmaf(x0, cw0, acc);
    acc = fmaf(x1, cw1, acc);
    acc = fmaf(x2, cw2, acc);
    acc = fmaf(x3, cw3, acc);
    const float uv = acc / (1.f + __expf(-acc));
    const int off = (b * L_SZ + l) * D_SZ + gi;
    u[off] = uv;
    const float dtv = dt[off];
    Tdt[ty + 8 * r][tx] = dtv;
    Tdu[ty + 8 * r][tx] = dtv * uv;
  }
  __syncthreads();
#pragma unroll
  for (int r = 0; r < 4; ++r) {
    const int il = ty + 8 * r;
    const int off = (b * D_SZ + i0 + il) * L_SZ + l0 + tx;
    dt_t[off] = Tdt[tx][il];
    dtu_t[off] = Tdu[tx][il];
  }
}

// ---------------------------------------------------------------------------
// Selective scan v18 = v12 structure (measured best: 64-thr waves, separate
// combine, XCD swizzle) with ONE change: Cm streamed as bf16 ushort loads.
// Diagnosis (R2..R7): VALU-busy time is constant 28-29us; stall tracks
// CACHE-LINE REQUEST count (R5: 3.7x lines -> 2.2x stall; TLP 9.7 vs 18
// waves/CU: no effect) -> L2 completion-rate-bound (~9 line-req/cyc/XCD at
// saturation). c-loads were 32 of ~35 lines/chunk (8 f32 rows x 4 lines);
// bf16 rows are 2 lines each -> ~19 lines/chunk (/1.85). Unpack = 8 shl.
// ---------------------------------------------------------------------------
struct ChunkS {
  f32x4 d0, d1, u0, u1;
  unsigned int c[8];   // bf16 in low 16 bits (ushort load zero-extends)
};

#define LOAD_CHUNK(K, B0, B1, B2, DTB, DUB)                                    \
  {                                                                            \
    asm volatile("global_load_dwordx4 %0, %1, off" : "=v"(K.d0) : "v"(DTB));   \
    asm volatile("global_load_dwordx4 %0, %1, off offset:16"                   \
                 : "=v"(K.d1) : "v"(DTB));                                     \
    asm volatile("global_load_dwordx4 %0, %1, off" : "=v"(K.u0) : "v"(DUB));   \
    asm volatile("global_load_dwordx4 %0, %1, off offset:16"                   \
                 : "=v"(K.u1) : "v"(DUB));                                     \
    asm volatile("global_load_ushort %0, %1, off" : "=v"(K.c[0]) : "v"(B0));   \
    asm volatile("global_load_ushort %0, %1, off offset:768"                   \
                 : "=v"(K.c[1]) : "v"(B0));                                    \
    asm volatile("global_load_ushort %0, %1, off offset:1536"                  \
                 : "=v"(K.c[2]) : "v"(B0));                                    \
    asm volatile("global_load_ushort %0, %1, off" : "=v"(K.c[3]) : "v"(B1));   \
    asm volatile("global_load_ushort %0, %1, off offset:768"                   \
                 : "=v"(K.c[4]) : "v"(B1));                                    \
    asm volatile("global_load_ushort %0, %1, off offset:1536"                  \
                 : "=v"(K.c[5]) : "v"(B1));                                    \
    asm volatile("global_load_ushort %0, %1, off" : "=v"(K.c[6]) : "v"(B2));   \
    asm volatile("global_load_ushort %0, %1, off offset:768"                   \
                 : "=v"(K.c[7]) : "v"(B2));                                    \
  }

#define WAIT_CHUNK(K)                                                          \
  asm volatile("s_waitcnt vmcnt(24)"                                           \
               : "+v"(K.d0), "+v"(K.d1), "+v"(K.u0), "+v"(K.u1),               \
                 "+v"(K.c[0]), "+v"(K.c[1]), "+v"(K.c[2]), "+v"(K.c[3]),       \
                 "+v"(K.c[4]), "+v"(K.c[5]), "+v"(K.c[6]), "+v"(K.c[7]))

#define ADV_BASES()                                                            \
  { cb0 += 3072; cb1 += 3072; cb2 += 3072; dtB += 8; duB += 8; }

__global__ __launch_bounds__(64, 4) void scan_kernel(
    const float* __restrict__ A_log, const float* __restrict__ dt_t,
    const float* __restrict__ dtu_t, const float* __restrict__ Bm,
    const unsigned short* __restrict__ Cmbf, float* __restrict__ part) {
  // XCD-aware remap (v12-proven): xcd = bid&7 owns contiguous sids.
  const int bid = blockIdx.x;        // 0..4607
  const int xcd = bid & 7;
  const int slot = bid >> 3;         // 0..575 within this XCD
  const int sid = xcd * 96 + slot / 6;
  const int w = slot % 6;            // j-split
  const int lane = threadIdx.x;      // 0..63
  const int b = sid / D_SZ;
  const int i = sid % D_SZ;
  const int j = w * 64 + lane;

  const float a2 = -__expf(A_log[i * S_SZ + j]) * LOG2E;
  const float bw = Bm[(b * D_SZ + i) * S_SZ + j];
  float h = 0.f;

  const float* dtB = dt_t + (b * D_SZ + i) * L_SZ;   // uniform, contiguous l
  const float* duB = dtu_t + (b * D_SZ + i) * L_SZ;
  // Cm (bf16) row bases: rows {0,1,2}, {3,4,5}, {6,7} of each chunk via
  // byte imm 0/768/1536 (row stride = 384*2B = 768B).
  const unsigned short* cmrow = Cmbf + b * BLK_ELEMS + j;
  const unsigned short* cb0 = cmrow;
  const unsigned short* cb1 = cmrow + 3 * S_SZ;
  const unsigned short* cb2 = cmrow + 6 * S_SZ;

  // fold result mapping: lane r holds value s = (b3<<2)|(b2<<1)|b0 of chunk;
  // lanes with bits {1,4,5} == 0 store (8 lanes cover s=0..7).
  const int sq = (((lane >> 3) & 1) << 2) | (((lane >> 2) & 1) << 1) | (lane & 1);
  const bool storer = (lane & 0x32) == 0;
  float* pstore = part + ((w * B_SZ + b) * D_SZ + i) * L_SZ + sq;

  // drain initial compiler loads so vmcnt counting is exact
  asm volatile("" :: "v"(a2), "v"(bw));
  asm volatile("s_waitcnt vmcnt(0)");

  auto compute_chunk = [&](ChunkS& K) {
    float acc[8];
    const float dts[8] = {K.d0[0], K.d0[1], K.d0[2], K.d0[3],
                          K.d1[0], K.d1[1], K.d1[2], K.d1[3]};
    const float dus[8] = {K.u0[0], K.u0[1], K.u0[2], K.u0[3],
                          K.u1[0], K.u1[1], K.u1[2], K.u1[3]};
#pragma unroll
    for (int s = 0; s < 8; ++s) {
      const float e = fexp2(dts[s] * a2);
      h = fmaf(e, h, bw * dus[s]);
      acc[s] = h * __uint_as_float(K.c[s] << 16);  // bf16 -> f32
    }
    // fold stage 1: pairing xor15 (row_mirror), side bit3, n2=4
    {
      const bool hi = (lane & 8) != 0;
#pragma unroll
      for (int q = 0; q < 4; ++q) {
        const float keep = hi ? acc[q + 4] : acc[q];
        const float send = hi ? acc[q] : acc[q + 4];
        acc[q] = keep + dpp_mov<0x140>(send);
      }
    }
    // fold stage 2: pairing xor7 (row_half_mirror), side bit2, n2=2
    {
      const bool hi = (lane & 4) != 0;
#pragma unroll
      for (int q = 0; q < 2; ++q) {
        const float keep = hi ? acc[q + 2] : acc[q];
        const float send = hi ? acc[q] : acc[q + 2];
        acc[q] = keep + dpp_mov<0x141>(send);
      }
    }
    // fold stage 3: pairing xor1 (quad_perm [1,0,3,2]), side bit0, n2=1
    {
      const bool hi = (lane & 1) != 0;
      const float keep = hi ? acc[1] : acc[0];
      const float send = hi ? acc[0] : acc[1];
      acc[0] = keep + dpp_mov<0xB1>(send);
    }
    // finish across unused bits {1,4,5}: all VALU-pipe lane exchanges
    float r = acc[0];
    r += dpp_mov<0x4E>(r);   // xor2: quad_perm [2,3,0,1]
    r = fold_xor16(r);       // xor16: permlane16_swap builtin
    r = fold_xor32(r);       // xor32: permlane32_swap builtin
    if (storer) *pstore = r;
    pstore += 8;
  };

  ChunkS K0, K1, K2;
  LOAD_CHUNK(K0, cb0, cb1, cb2, dtB, duB);
  ADV_BASES();
  LOAD_CHUNK(K1, cb0, cb1, cb2, dtB, duB);
  ADV_BASES();
#pragma unroll 1
  for (int it = 0; it < 16; ++it) {
    LOAD_CHUNK(K2, cb0, cb1, cb2, dtB, duB);
    ADV_BASES();
    WAIT_CHUNK(K0);
    compute_chunk(K0);
    LOAD_CHUNK(K0, cb0, cb1, cb2, dtB, duB);
    ADV_BASES();
    WAIT_CHUNK(K1);
    compute_chunk(K1);
    LOAD_CHUNK(K1, cb0, cb1, cb2, dtB, duB);
    ADV_BASES();
    WAIT_CHUNK(K2);
    compute_chunk(K2);
  }
  // 48 chunks computed; the 2 dangling prefetched chunks are never waited
  // on and write only dead registers (kernel ends here — v16's crash was
  // from ADDING code after this point). Their Cm overreads stay inside the
  // bf16 workspace area (Cmbf is followed by xdblbf), dt/dtu overreads
  // land in the adjacent f32 slots.
}

// ---------------------------------------------------------------------------
// Combine + transpose: y[b,l,i] = sum_{w<6} part[w][b][i][l] + u[b,l,i]*D[i]
// (R2-proven; fusion into the scan measured WORSE in R7 — uncoalesced tail)
// ---------------------------------------------------------------------------
__global__ __launch_bounds__(256) void combine_kernel(
    const float* __restrict__ part, const float* __restrict__ u,
    const float* __restrict__ Dv, float* __restrict__ y) {
  __shared__ float T[32][33];
  const int tx = threadIdx.x;
  const int ty0 = threadIdx.y;
  const int b = blockIdx.z;
  const int i0 = blockIdx.y * 32;
  const int l0 = blockIdx.x * 32;
#pragma unroll
  for (int r = 0; r < 4; ++r) {
    const int il = ty0 + 8 * r;
    float s = 0.f;
#pragma unroll
    for (int w = 0; w < 6; ++w)
      s += part[((w * B_SZ + b) * D_SZ + i0 + il) * L_SZ + l0 + tx];
    T[il][tx] = s;
  }
  __syncthreads();
#pragma unroll
  for (int r = 0; r < 4; ++r) {
    const int ll = ty0 + 8 * r;
    const int gi = i0 + tx;
    const int off = (b * L_SZ + l0 + ll) * D_SZ + gi;
    y[off] = fmaf(u[off], Dv[gi], T[tx][ll]);
  }
}

extern "C" void kernel_launch(void* const* d_in, const int* in_sizes, int n_in,
                              void* d_out, int out_size, void* d_ws,
                              size_t ws_size, hipStream_t stream) {
  const float* x = (const float*)d_in[0];
  const float* A_log = (const float*)d_in[1];
  const float* D = (const float*)d_in[2];
  const float* dt_w = (const float*)d_in[3];
  const float* dt_b = (const float*)d_in[4];
  const float* B_w = (const float*)d_in[5];
  const float* C_w = (const float*)d_in[6];
  const float* conv_w = (const float*)d_in[7];
  const float* conv_b = (const float*)d_in[8];
  float* y = (float*)d_out;

  float* ws = (float*)d_ws;
  float* dt = ws;                     // slot 0  [b,l,i]
  float* u = ws + TOT_ELEMS;          // slot 1
  float* Bm = ws + 2 * TOT_ELEMS;     // slot 2
  float* dt_t = ws + 3 * TOT_ELEMS;   // slot 3  [b,i,l]
  float* dtu_t = ws + 4 * TOT_ELEMS;  // slot 4  [b,i,l]
  float* part = ws + 5 * TOT_ELEMS;   // slots 5..10  [w][b][i][l], w<6
  unsigned short* bfarea = (unsigned short*)(ws + 11 * TOT_ELEMS);
  unsigned short* Cmbf = bfarea;              // 294912 (scan overreads spill
  unsigned short* xdblbf = bfarea + TOT_ELEMS;// 294912  into xdblbf: safe)

  mfma_dual_gemm<1><<<dim3(24, 24), 128, 0, stream>>>(x, dt_w, B_w, dt_b, dt, xdblbf);
  mfma_dual_gemm<2><<<dim3(24, 24), 128, 0, stream>>>(xdblbf, B_w, C_w, nullptr, Bm, Cmbf);
  conv_tr_kernel<<<dim3(L_SZ / 32, D_SZ / 32, B_SZ), dim3(32, 8), 0, stream>>>(
      x, conv_w, conv_b, dt, u, dt_t, dtu_t);
  scan_kernel<<<4608, 64, 0, stream>>>(A_log, dt_t, dtu_t, Bm, Cmbf, part);
  combine_kernel<<<dim3(L_SZ / 32, D_SZ / 32, B_SZ), dim3(32, 8), 0, stream>>>(
      part, u, D, y);
}

// Round 9
// 131.667 us; speedup vs baseline: 1.3083x; 1.0429x over previous
//
#include <hip/hip_runtime.h>
#include <math.h>

// Dims (fixed by the problem)
#define B_SZ 2
#define L_SZ 384
#define D_SZ 384
#define S_SZ 384
#define BLK_ELEMS (L_SZ * D_SZ)        // 147456 per batch
#define TOT_ELEMS (B_SZ * L_SZ * D_SZ) // 294912
#define LOG2E 1.4426950408889634f

typedef __attribute__((ext_vector_type(8))) short bf16x8;
typedef __attribute__((ext_vector_type(4))) float f32x4;
typedef __attribute__((ext_vector_type(2))) unsigned int u32x2;

__device__ __forceinline__ float fexp2(float x) {
  return __builtin_amdgcn_exp2f(x);
}
__device__ __forceinline__ float softplus_f(float z) {
  return (z > 20.f) ? z : log1pf(__expf(z));
}
__device__ __forceinline__ unsigned short f2bf(float f) {  // RNE f32->bf16
  unsigned int u = __float_as_uint(f);
  return (unsigned short)((u + 0x7FFFu + ((u >> 16) & 1u)) >> 16);
}
#define PIPELINE_FENCE() asm volatile("" ::: "memory")

// 8x f32 -> 8x bf16 (RNE) via v_cvt_pk_bf16_f32 (plain VALU asm — no
// hazard class, unlike permlane).
__device__ __forceinline__ bf16x8 cvt8(const float* p) {
  const f32x4 v0 = *(const f32x4*)p;
  const f32x4 v1 = *(const f32x4*)(p + 4);
  union { unsigned int u[4]; bf16x8 v; } r;
  asm("v_cvt_pk_bf16_f32 %0, %1, %2" : "=v"(r.u[0]) : "v"(v0[0]), "v"(v0[1]));
  asm("v_cvt_pk_bf16_f32 %0, %1, %2" : "=v"(r.u[1]) : "v"(v0[2]), "v"(v0[3]));
  asm("v_cvt_pk_bf16_f32 %0, %1, %2" : "=v"(r.u[2]) : "v"(v1[0]), "v"(v1[1]));
  asm("v_cvt_pk_bf16_f32 %0, %1, %2" : "=v"(r.u[3]) : "v"(v1[2]), "v"(v1[3]));
  return r.v;
}

// DPP lane exchange (VALU pipe). CTRL: 0x140=row_mirror (xor15),
// 0x141=row_half_mirror (xor7), 0xB1=quad_perm[1,0,3,2] (xor1),
// 0x4E=quad_perm[2,3,0,1] (xor2).
template <int CTRL>
__device__ __forceinline__ float dpp_mov(float v) {
  return __int_as_float(
      __builtin_amdgcn_update_dpp(0, __float_as_int(v), CTRL, 0xF, 0xF, true));
}

// r + shfl_xor(r,16)/(r,32) in ALL lanes via permlane*_swap BUILTINS
// (raw asm hit the gfx950 VALU-write->permlane wait-state hazard, v13).
__device__ __forceinline__ float fold_xor16(float r) {
#if __has_builtin(__builtin_amdgcn_permlane16_swap)
  const unsigned ru = __float_as_uint(r);
  u32x2 p = __builtin_amdgcn_permlane16_swap(ru, ru, false, false);
  return __uint_as_float(p[0]) + __uint_as_float(p[1]);
#else
  return r + __shfl_xor(r, 16, 64);
#endif
}
__device__ __forceinline__ float fold_xor32(float r) {
#if __has_builtin(__builtin_amdgcn_permlane32_swap)
  const unsigned ru = __float_as_uint(r);
  u32x2 p = __builtin_amdgcn_permlane32_swap(ru, ru, false, false);
  return __uint_as_float(p[0]) + __uint_as_float(p[1]);
#else
  return r + __shfl_xor(r, 32, 64);
#endif
}

// ---------------------------------------------------------------------------
// LDS-staged dual MFMA NT-GEMM (R8 version, unchanged).
// ---------------------------------------------------------------------------
template <int MODE>
__global__ __launch_bounds__(128, 2) void mfma_dual_gemm(
    const void* __restrict__ Av, const float* __restrict__ W1,
    const float* __restrict__ W2, const float* __restrict__ bias,
    float* __restrict__ O1, unsigned short* __restrict__ O2) {
  __shared__ unsigned short sA[32 * 392];
  __shared__ unsigned short sW1[16 * 392];
  __shared__ unsigned short sW2[16 * 392];

  const int t = threadIdx.x;
  const int wv = t >> 6;
  const int lane = t & 63;
  const int nt = blockIdx.x;
  const int mrow = blockIdx.y;

  const float* W1b = W1 + nt * 16 * 384;
  const float* W2b = W2 + nt * 16 * 384;

  if constexpr (MODE == 1) {
    const float* Ab = (const float*)Av + mrow * 32 * 384;
#pragma unroll
    for (int it = 0; it < 12; ++it) {
      const int id = t + it * 128;
      const int row = id / 48, col = id - row * 48;
      *(bf16x8*)&sA[row * 392 + col * 8] = cvt8(Ab + id * 8);
    }
  } else {
    const unsigned short* Ab = (const unsigned short*)Av + mrow * 32 * 384;
#pragma unroll
    for (int it = 0; it < 12; ++it) {
      const int id = t + it * 128;
      const int row = id / 48, col = id - row * 48;
      *(bf16x8*)&sA[row * 392 + col * 8] = *(const bf16x8*)(Ab + id * 8);
    }
  }
#pragma unroll
  for (int it = 0; it < 6; ++it) {
    const int id = t + it * 128;
    const int row = id / 48, col = id - row * 48;
    *(bf16x8*)&sW1[row * 392 + col * 8] = cvt8(W1b + id * 8);
    *(bf16x8*)&sW2[row * 392 + col * 8] = cvt8(W2b + id * 8);
  }
  __syncthreads();

  const int rc = lane & 15;
  const int quad = lane >> 4;
  bf16x8 af[12], w1f[12], w2f[12];
#pragma unroll
  for (int kt = 0; kt < 12; ++kt) {
    af[kt] = *(const bf16x8*)&sA[(wv * 16 + rc) * 392 + quad * 8 + kt * 32];
    w1f[kt] = *(const bf16x8*)&sW1[rc * 392 + quad * 8 + kt * 32];
    w2f[kt] = *(const bf16x8*)&sW2[rc * 392 + quad * 8 + kt * 32];
  }
  PIPELINE_FENCE();
  f32x4 acc1 = {0.f, 0.f, 0.f, 0.f};
  f32x4 acc2 = {0.f, 0.f, 0.f, 0.f};
#pragma unroll
  for (int kt = 0; kt < 12; ++kt) {
    acc1 = __builtin_amdgcn_mfma_f32_16x16x32_bf16(af[kt], w1f[kt], acc1, 0, 0, 0);
    acc2 = __builtin_amdgcn_mfma_f32_16x16x32_bf16(af[kt], w2f[kt], acc2, 0, 0, 0);
  }
  const int col = nt * 16 + rc;
  const int row0 = mrow * 32 + wv * 16 + quad * 4;
  if constexpr (MODE == 1) {
    const float bb = bias[col];
#pragma unroll
    for (int r = 0; r < 4; ++r) {
      O1[(row0 + r) * 384 + col] = softplus_f(acc1[r] + bb);
      O2[(row0 + r) * 384 + col] = f2bf(acc2[r]);
    }
  } else {
#pragma unroll
    for (int r = 0; r < 4; ++r) {
      O1[(row0 + r) * 384 + col] = acc1[r];
      O2[(row0 + r) * 384 + col] = f2bf(acc2[r]);
    }
  }
}

// ---------------------------------------------------------------------------
// Conv + SiLU + transpose (unchanged).
// ---------------------------------------------------------------------------
__global__ __launch_bounds__(256) void conv_tr_kernel(
    const float* __restrict__ x, const float* __restrict__ cw,
    const float* __restrict__ cb, const float* __restrict__ dt,
    float* __restrict__ u, float* __restrict__ dt_t,
    float* __restrict__ dtu_t) {
  __shared__ float Tdt[32][33];
  __shared__ float Tdu[32][33];
  const int tx = threadIdx.x;
  const int ty = threadIdx.y;
  const int b = blockIdx.z;
  const int i0 = blockIdx.y * 32;
  const int l0 = blockIdx.x * 32;
  const int gi = i0 + tx;
  const float cbv = cb[gi];
  const float cw0 = cw[gi * 4 + 0], cw1 = cw[gi * 4 + 1];
  const float cw2 = cw[gi * 4 + 2], cw3 = cw[gi * 4 + 3];
#pragma unroll
  for (int r = 0; r < 4; ++r) {
    const int l = l0 + ty + 8 * r;
    float acc = cbv;
    const float x3 = x[(b * L_SZ + l) * D_SZ + gi];
    const float x2 = (l >= 1) ? x[(b * L_SZ + l - 1) * D_SZ + gi] : 0.f;
    const float x1 = (l >= 2) ? x[(b * L_SZ + l - 2) * D_SZ + gi] : 0.f;
    const float x0 = (l >= 3) ? x[(b * L_SZ + l - 3) * D_SZ + gi] : 0.f;
    acc = fmaf(x0, cw0, acc);
    acc = fmaf(x1, cw1, acc);
    acc = fmaf(x2, cw2, acc);
    acc = fmaf(x3, cw3, acc);
    const float uv = acc / (1.f + __expf(-acc));
    const int off = (b * L_SZ + l) * D_SZ + gi;
    u[off] = uv;
    const float dtv = dt[off];
    Tdt[ty + 8 * r][tx] = dtv;
    Tdu[ty + 8 * r][tx] = dtv * uv;
  }
  __syncthreads();
#pragma unroll
  for (int r = 0; r < 4; ++r) {
    const int il = ty + 8 * r;
    const int off = (b * D_SZ + i0 + il) * L_SZ + l0 + tx;
    dt_t[off] = Tdt[tx][il];
    dtu_t[off] = Tdu[tx][il];
  }
}

// ---------------------------------------------------------------------------
// Selective scan v19 = v18 (bf16 Cm, best) + dt/dtu moved to the SCALAR
// path. Model from R2/R8: stall = 1.37us per VMEM-instr/chunk + 0.28us per
// line/chunk; the instruction term dominates (12 x 1.37 = 16.5 of 22us).
// dt/dtu loads are wave-uniform -> s_load_dwordx4 (scalar cache, lgkmcnt,
// zero vector-path cost). SMEM returns may be out-of-order, so only
// lgkmcnt(0) is safe: wait-then-issue-next discipline, 2 S-buffers, loop
// body = 6 chunks so K-period(3) and S-period(2) both divide it. Scan has
// no DS ops, so lgkmcnt is SMEM-only here. VMEM instr/chunk 12 -> 8
// (all c ushort loads); WAIT vmcnt(16) = 2 chunks outstanding.
// ---------------------------------------------------------------------------
struct CChunk {
  unsigned int c[8];   // bf16 in low 16 bits (ushort load zero-extends)
};
struct SChunk {
  f32x4 d0, d1, u0, u1;  // dt[0..7], dtu[0..7] in SGPRs
};

#define LOAD_CHUNK(K, B0, B1, B2)                                              \
  {                                                                            \
    asm volatile("global_load_ushort %0, %1, off" : "=v"(K.c[0]) : "v"(B0));   \
    asm volatile("global_load_ushort %0, %1, off offset:768"                   \
                 : "=v"(K.c[1]) : "v"(B0));                                    \
    asm volatile("global_load_ushort %0, %1, off offset:1536"                  \
                 : "=v"(K.c[2]) : "v"(B0));                                    \
    asm volatile("global_load_ushort %0, %1, off" : "=v"(K.c[3]) : "v"(B1));   \
    asm volatile("global_load_ushort %0, %1, off offset:768"                   \
                 : "=v"(K.c[4]) : "v"(B1));                                    \
    asm volatile("global_load_ushort %0, %1, off offset:1536"                  \
                 : "=v"(K.c[5]) : "v"(B1));                                    \
    asm volatile("global_load_ushort %0, %1, off" : "=v"(K.c[6]) : "v"(B2));   \
    asm volatile("global_load_ushort %0, %1, off offset:768"                   \
                 : "=v"(K.c[7]) : "v"(B2));                                    \
  }

#define WAIT_CHUNK(K)                                                          \
  asm volatile("s_waitcnt vmcnt(16)"                                           \
               : "+v"(K.c[0]), "+v"(K.c[1]), "+v"(K.c[2]), "+v"(K.c[3]),       \
                 "+v"(K.c[4]), "+v"(K.c[5]), "+v"(K.c[6]), "+v"(K.c[7]))

#define SLOAD_CHUNK(S, SDT, SDU)                                               \
  asm volatile("s_load_dwordx4 %0, %4, 0x0\n\t"                                \
               "s_load_dwordx4 %1, %4, 0x10\n\t"                               \
               "s_load_dwordx4 %2, %5, 0x0\n\t"                                \
               "s_load_dwordx4 %3, %5, 0x10"                                   \
               : "=&s"(S.d0), "=&s"(S.d1), "=&s"(S.u0), "=&s"(S.u1)            \
               : "s"(SDT), "s"(SDU));

#define SWAIT(S)                                                               \
  asm volatile("s_waitcnt lgkmcnt(0)"                                          \
               : "+s"(S.d0), "+s"(S.d1), "+s"(S.u0), "+s"(S.u1))

#define ADV_BASES()                                                            \
  { cb0 += 3072; cb1 += 3072; cb2 += 3072; }
#define SADV()                                                                 \
  { sdt += 8; sdu += 8; }

__global__ __launch_bounds__(64, 4) void scan_kernel(
    const float* __restrict__ A_log, const float* __restrict__ dt_t,
    const float* __restrict__ dtu_t, const float* __restrict__ Bm,
    const unsigned short* __restrict__ Cmbf, float* __restrict__ part) {
  // XCD-aware remap (v12-proven): xcd = bid&7 owns contiguous sids.
  const int bid = blockIdx.x;        // 0..4607
  const int xcd = bid & 7;
  const int slot = bid >> 3;         // 0..575 within this XCD
  const int sid = xcd * 96 + slot / 6;
  const int w = slot % 6;            // j-split
  const int lane = threadIdx.x;      // 0..63
  const int b = sid / D_SZ;
  const int i = sid % D_SZ;
  const int j = w * 64 + lane;

  const float a2 = -__expf(A_log[i * S_SZ + j]) * LOG2E;
  const float bw = Bm[(b * D_SZ + i) * S_SZ + j];
  float h = 0.f;

  const float* sdt = dt_t + (b * D_SZ + i) * L_SZ;   // uniform -> SMEM
  const float* sdu = dtu_t + (b * D_SZ + i) * L_SZ;  // uniform -> SMEM
  // Cm (bf16) row bases: rows {0,1,2}, {3,4,5}, {6,7} of each chunk via
  // byte imm 0/768/1536 (row stride = 384*2B = 768B).
  const unsigned short* cmrow = Cmbf + b * BLK_ELEMS + j;
  const unsigned short* cb0 = cmrow;
  const unsigned short* cb1 = cmrow + 3 * S_SZ;
  const unsigned short* cb2 = cmrow + 6 * S_SZ;

  // fold result mapping: lane r holds value s = (b3<<2)|(b2<<1)|b0 of chunk;
  // lanes with bits {1,4,5} == 0 store (8 lanes cover s=0..7).
  const int sq = (((lane >> 3) & 1) << 2) | (((lane >> 2) & 1) << 1) | (lane & 1);
  const bool storer = (lane & 0x32) == 0;
  float* pstore = part + ((w * B_SZ + b) * D_SZ + i) * L_SZ + sq;

  // drain initial compiler loads so vmcnt counting is exact
  asm volatile("" :: "v"(a2), "v"(bw));
  asm volatile("s_waitcnt vmcnt(0)");

  auto compute_chunk = [&](CChunk& K, SChunk& S) {
    float acc[8];
    const float dts[8] = {S.d0[0], S.d0[1], S.d0[2], S.d0[3],
                          S.d1[0], S.d1[1], S.d1[2], S.d1[3]};
    const float dus[8] = {S.u0[0], S.u0[1], S.u0[2], S.u0[3],
                          S.u1[0], S.u1[1], S.u1[2], S.u1[3]};
#pragma unroll
    for (int s = 0; s < 8; ++s) {
      const float e = fexp2(dts[s] * a2);
      h = fmaf(e, h, bw * dus[s]);
      acc[s] = h * __uint_as_float(K.c[s] << 16);  // bf16 -> f32
    }
    // fold stage 1: pairing xor15 (row_mirror), side bit3, n2=4
    {
      const bool hi = (lane & 8) != 0;
#pragma unroll
      for (int q = 0; q < 4; ++q) {
        const float keep = hi ? acc[q + 4] : acc[q];
        const float send = hi ? acc[q] : acc[q + 4];
        acc[q] = keep + dpp_mov<0x140>(send);
      }
    }
    // fold stage 2: pairing xor7 (row_half_mirror), side bit2, n2=2
    {
      const bool hi = (lane & 4) != 0;
#pragma unroll
      for (int q = 0; q < 2; ++q) {
        const float keep = hi ? acc[q + 2] : acc[q];
        const float send = hi ? acc[q] : acc[q + 2];
        acc[q] = keep + dpp_mov<0x141>(send);
      }
    }
    // fold stage 3: pairing xor1 (quad_perm [1,0,3,2]), side bit0, n2=1
    {
      const bool hi = (lane & 1) != 0;
      const float keep = hi ? acc[1] : acc[0];
      const float send = hi ? acc[0] : acc[1];
      acc[0] = keep + dpp_mov<0xB1>(send);
    }
    // finish across unused bits {1,4,5}: all VALU-pipe lane exchanges
    float r = acc[0];
    r += dpp_mov<0x4E>(r);   // xor2: quad_perm [2,3,0,1]
    r = fold_xor16(r);       // xor16: permlane16_swap builtin
    r = fold_xor32(r);       // xor32: permlane32_swap builtin
    if (storer) *pstore = r;
    pstore += 8;
  };

  CChunk K0, K1, K2;
  SChunk S0, S1;
  LOAD_CHUNK(K0, cb0, cb1, cb2);   // chunk 0 (VMEM)
  ADV_BASES();
  LOAD_CHUNK(K1, cb0, cb1, cb2);   // chunk 1 (VMEM)
  ADV_BASES();
  SLOAD_CHUNK(S0, sdt, sdu);       // chunk 0 (SMEM)
  SADV();

  // Per step (chunk c): LOAD c+2 (VMEM); WAIT chunk c (vmcnt 16);
  // SWAIT chunk c (lgkmcnt 0 — issued one compute ago); SLOAD c+1;
  // compute. 6 steps/iter so K(3) and S(2) rotations both close.
#define STEP(KC, SC, SN)                                                       \
  LOAD_CHUNK(KC, cb0, cb1, cb2);                                               \
  ADV_BASES();                                                                 \
  WAIT_CHUNK(KC##_wait);                                                       \
  SWAIT(SC);                                                                   \
  SLOAD_CHUNK(SN, sdt, sdu);                                                   \
  SADV();                                                                      \
  compute_chunk(KC##_wait, SC);

#pragma unroll 1
  for (int it = 0; it < 8; ++it) {
    // c = 6*it + 0 .. 5 ; K rotation: compute K0,K1,K2,K0,K1,K2;
    // load into K2,K0,K1,K2,K0,K1 ; S alternates S0,S1,...
    { CChunk& K2_wait = K0; STEP(K2, S0, S1); }
    { CChunk& K0_wait = K1; STEP(K0, S1, S0); }
    { CChunk& K1_wait = K2; STEP(K1, S0, S1); }
    { CChunk& K2_wait = K0; STEP(K2, S1, S0); }
    { CChunk& K0_wait = K1; STEP(K0, S0, S1); }
    { CChunk& K1_wait = K2; STEP(K1, S1, S0); }
  }
#undef STEP
  // 48 chunks computed; dangling prefetches (2 VMEM chunks + 1 SMEM chunk)
  // write only dead registers — kernel ends here (v16 lesson: never add
  // code after this point). Overreads stay inside the workspace: Cm reads
  // stay within Cmbf (b=1 worst case ~446KB < 576KB), dt/dtu reads land in
  // the adjacent slot.
}

// ---------------------------------------------------------------------------
// Combine + transpose: y[b,l,i] = sum_{w<6} part[w][b][i][l] + u[b,l,i]*D[i]
// ---------------------------------------------------------------------------
__global__ __launch_bounds__(256) void combine_kernel(
    const float* __restrict__ part, const float* __restrict__ u,
    const float* __restrict__ Dv, float* __restrict__ y) {
  __shared__ float T[32][33];
  const int tx = threadIdx.x;
  const int ty0 = threadIdx.y;
  const int b = blockIdx.z;
  const int i0 = blockIdx.y * 32;
  const int l0 = blockIdx.x * 32;
#pragma unroll
  for (int r = 0; r < 4; ++r) {
    const int il = ty0 + 8 * r;
    float s = 0.f;
#pragma unroll
    for (int w = 0; w < 6; ++w)
      s += part[((w * B_SZ + b) * D_SZ + i0 + il) * L_SZ + l0 + tx];
    T[il][tx] = s;
  }
  __syncthreads();
#pragma unroll
  for (int r = 0; r < 4; ++r) {
    const int ll = ty0 + 8 * r;
    const int gi = i0 + tx;
    const int off = (b * L_SZ + l0 + ll) * D_SZ + gi;
    y[off] = fmaf(u[off], Dv[gi], T[tx][ll]);
  }
}

extern "C" void kernel_launch(void* const* d_in, const int* in_sizes, int n_in,
                              void* d_out, int out_size, void* d_ws,
                              size_t ws_size, hipStream_t stream) {
  const float* x = (const float*)d_in[0];
  const float* A_log = (const float*)d_in[1];
  const float* D = (const float*)d_in[2];
  const float* dt_w = (const float*)d_in[3];
  const float* dt_b = (const float*)d_in[4];
  const float* B_w = (const float*)d_in[5];
  const float* C_w = (const float*)d_in[6];
  const float* conv_w = (const float*)d_in[7];
  const float* conv_b = (const float*)d_in[8];
  float* y = (float*)d_out;

  float* ws = (float*)d_ws;
  float* dt = ws;                     // slot 0  [b,l,i]
  float* u = ws + TOT_ELEMS;          // slot 1
  float* Bm = ws + 2 * TOT_ELEMS;     // slot 2
  float* dt_t = ws + 3 * TOT_ELEMS;   // slot 3  [b,i,l]
  float* dtu_t = ws + 4 * TOT_ELEMS;  // slot 4  [b,i,l]
  float* part = ws + 5 * TOT_ELEMS;   // slots 5..10  [w][b][i][l], w<6
  unsigned short* bfarea = (unsigned short*)(ws + 11 * TOT_ELEMS);
  unsigned short* Cmbf = bfarea;              // 294912 (scan overreads spill
  unsigned short* xdblbf = bfarea + TOT_ELEMS;// 294912  into xdblbf: safe)

  mfma_dual_gemm<1><<<dim3(24, 24), 128, 0, stream>>>(x, dt_w, B_w, dt_b, dt, xdblbf);
  mfma_dual_gemm<2><<<dim3(24, 24), 128, 0, stream>>>(xdblbf, B_w, C_w, nullptr, Bm, Cmbf);
  conv_tr_kernel<<<dim3(L_SZ / 32, D_SZ / 32, B_SZ), dim3(32, 8), 0, stream>>>(
      x, conv_w, conv_b, dt, u, dt_t, dtu_t);
  scan_kernel<<<4608, 64, 0, stream>>>(A_log, dt_t, dtu_t, Bm, Cmbf, part);
  combine_kernel<<<dim3(L_SZ / 32, D_SZ / 32, B_SZ), dim3(32, 8), 0, stream>>>(
      part, u, D, y);
}

// Round 13
// 128.098 us; speedup vs baseline: 1.3447x; 1.0279x over previous
//
#include <hip/hip_runtime.h>
#include <math.h>

// Dims (fixed by the problem)
#define B_SZ 2
#define L_SZ 384
#define D_SZ 384
#define S_SZ 384
#define BLK_ELEMS (L_SZ * D_SZ)        // 147456 per batch
#define TOT_ELEMS (B_SZ * L_SZ * D_SZ) // 294912
#define LOG2E 1.4426950408889634f

typedef __attribute__((ext_vector_type(8))) short bf16x8;
typedef __attribute__((ext_vector_type(4))) float f32x4;
typedef __attribute__((ext_vector_type(2))) unsigned int u32x2;

__device__ __forceinline__ float fexp2(float x) {
  return __builtin_amdgcn_exp2f(x);
}
__device__ __forceinline__ float softplus_f(float z) {
  return (z > 20.f) ? z : log1pf(__expf(z));
}
__device__ __forceinline__ unsigned short f2bf(float f) {  // RNE f32->bf16
  unsigned int u = __float_as_uint(f);
  return (unsigned short)((u + 0x7FFFu + ((u >> 16) & 1u)) >> 16);
}
#define PIPELINE_FENCE() asm volatile("" ::: "memory")

// 8x f32 -> 8x bf16 (RNE) via v_cvt_pk_bf16_f32. SAFE here: inputs come
// from memory loads (counter-based waitcnts cover asm operands). NOT safe
// for MFMA results — see GEMM2 epilogue note.
__device__ __forceinline__ bf16x8 cvt8(const float* p) {
  const f32x4 v0 = *(const f32x4*)p;
  const f32x4 v1 = *(const f32x4*)(p + 4);
  union { unsigned int u[4]; bf16x8 v; } r;
  asm("v_cvt_pk_bf16_f32 %0, %1, %2" : "=v"(r.u[0]) : "v"(v0[0]), "v"(v0[1]));
  asm("v_cvt_pk_bf16_f32 %0, %1, %2" : "=v"(r.u[1]) : "v"(v0[2]), "v"(v0[3]));
  asm("v_cvt_pk_bf16_f32 %0, %1, %2" : "=v"(r.u[2]) : "v"(v1[0]), "v"(v1[1]));
  asm("v_cvt_pk_bf16_f32 %0, %1, %2" : "=v"(r.u[3]) : "v"(v1[2]), "v"(v1[3]));
  return r.v;
}

// DPP lane exchange (VALU pipe). CTRL: 0x140=row_mirror (xor15),
// 0x141=row_half_mirror (xor7), 0xB1=quad_perm[1,0,3,2] (xor1),
// 0x4E=quad_perm[2,3,0,1] (xor2).
template <int CTRL>
__device__ __forceinline__ float dpp_mov(float v) {
  return __int_as_float(
      __builtin_amdgcn_update_dpp(0, __float_as_int(v), CTRL, 0xF, 0xF, true));
}

// r + shfl_xor(r,16)/(r,32) in ALL lanes via permlane*_swap BUILTINS
// (raw asm hit the gfx950 VALU-write->permlane wait-state hazard, v13).
__device__ __forceinline__ float fold_xor16(float r) {
#if __has_builtin(__builtin_amdgcn_permlane16_swap)
  const unsigned ru = __float_as_uint(r);
  u32x2 p = __builtin_amdgcn_permlane16_swap(ru, ru, false, false);
  return __uint_as_float(p[0]) + __uint_as_float(p[1]);
#else
  return r + __shfl_xor(r, 16, 64);
#endif
}
__device__ __forceinline__ float fold_xor32(float r) {
#if __has_builtin(__builtin_amdgcn_permlane32_swap)
  const unsigned ru = __float_as_uint(r);
  u32x2 p = __builtin_amdgcn_permlane32_swap(ru, ru, false, false);
  return __uint_as_float(p[0]) + __uint_as_float(p[1]);
#else
  return r + __shfl_xor(r, 32, 64);
#endif
}

// ---------------------------------------------------------------------------
// LDS-staged dual MFMA NT-GEMM. MODE 1: A=f32 (x), O1=softplus dt, O2=xdbl
// bf16 row-major. MODE 2: A=bf16, O1=Bm f32, O2=Cm PACKED u32x2 per
// (l-group of 4, col): {pack(l0,l1), pack(l2,l3)}.
// v20-22 post-mortem (3x NaN): the packed epilogue used inline-asm cvt_pk
// READING acc2 RIGHT AFTER THE MFMA LOOP — the MFMA-dst->VALU-read
// wait-state hazard is invisible through inline asm (v13 lesson, MFMA
// flavor), so the asm read a mid-flight accumulator -> garbage bf16 ->
// NaN bit patterns -> NaN output. Fix: pack in PLAIN C via f2bf (compiler
// sees the reads, inserts hazard NOPs — the path MODE 1 has always used).
// ---------------------------------------------------------------------------
template <int MODE>
__global__ __launch_bounds__(128, 2) void mfma_dual_gemm(
    const void* __restrict__ Av, const float* __restrict__ W1,
    const float* __restrict__ W2, const float* __restrict__ bias,
    float* __restrict__ O1, void* __restrict__ O2v) {
  __shared__ unsigned short sA[32 * 392];
  __shared__ unsigned short sW1[16 * 392];
  __shared__ unsigned short sW2[16 * 392];

  const int t = threadIdx.x;
  const int wv = t >> 6;
  const int lane = t & 63;
  const int nt = blockIdx.x;
  const int mrow = blockIdx.y;

  const float* W1b = W1 + nt * 16 * 384;
  const float* W2b = W2 + nt * 16 * 384;

  if constexpr (MODE == 1) {
    const float* Ab = (const float*)Av + mrow * 32 * 384;
#pragma unroll
    for (int it = 0; it < 12; ++it) {
      const int id = t + it * 128;
      const int row = id / 48, col = id - row * 48;
      *(bf16x8*)&sA[row * 392 + col * 8] = cvt8(Ab + id * 8);
    }
  } else {
    const unsigned short* Ab = (const unsigned short*)Av + mrow * 32 * 384;
#pragma unroll
    for (int it = 0; it < 12; ++it) {
      const int id = t + it * 128;
      const int row = id / 48, col = id - row * 48;
      *(bf16x8*)&sA[row * 392 + col * 8] = *(const bf16x8*)(Ab + id * 8);
    }
  }
#pragma unroll
  for (int it = 0; it < 6; ++it) {
    const int id = t + it * 128;
    const int row = id / 48, col = id - row * 48;
    *(bf16x8*)&sW1[row * 392 + col * 8] = cvt8(W1b + id * 8);
    *(bf16x8*)&sW2[row * 392 + col * 8] = cvt8(W2b + id * 8);
  }
  __syncthreads();

  const int rc = lane & 15;
  const int quad = lane >> 4;
  bf16x8 af[12], w1f[12], w2f[12];
#pragma unroll
  for (int kt = 0; kt < 12; ++kt) {
    af[kt] = *(const bf16x8*)&sA[(wv * 16 + rc) * 392 + quad * 8 + kt * 32];
    w1f[kt] = *(const bf16x8*)&sW1[rc * 392 + quad * 8 + kt * 32];
    w2f[kt] = *(const bf16x8*)&sW2[rc * 392 + quad * 8 + kt * 32];
  }
  PIPELINE_FENCE();
  f32x4 acc1 = {0.f, 0.f, 0.f, 0.f};
  f32x4 acc2 = {0.f, 0.f, 0.f, 0.f};
#pragma unroll
  for (int kt = 0; kt < 12; ++kt) {
    acc1 = __builtin_amdgcn_mfma_f32_16x16x32_bf16(af[kt], w1f[kt], acc1, 0, 0, 0);
    acc2 = __builtin_amdgcn_mfma_f32_16x16x32_bf16(af[kt], w2f[kt], acc2, 0, 0, 0);
  }
  const int col = nt * 16 + rc;
  const int row0 = mrow * 32 + wv * 16 + quad * 4;   // multiple of 4
  if constexpr (MODE == 1) {
    unsigned short* O2 = (unsigned short*)O2v;
    const float bb = bias[col];
#pragma unroll
    for (int r = 0; r < 4; ++r) {
      O1[(row0 + r) * 384 + col] = softplus_f(acc1[r] + bb);
      O2[(row0 + r) * 384 + col] = f2bf(acc2[r]);
    }
  } else {
#pragma unroll
    for (int r = 0; r < 4; ++r)
      O1[(row0 + r) * 384 + col] = acc1[r];
    // Plain-C pack (hazard-safe): compiler-emitted reads of acc2 get the
    // required MFMA-read wait states.
    const unsigned int p01 =
        (unsigned int)f2bf(acc2[0]) | ((unsigned int)f2bf(acc2[1]) << 16);
    const unsigned int p23 =
        (unsigned int)f2bf(acc2[2]) | ((unsigned int)f2bf(acc2[3]) << 16);
    u32x2 q = {p01, p23};
    *((u32x2*)O2v + ((row0 >> 2) * 384 + col)) = q;
  }
}

// ---------------------------------------------------------------------------
// Conv + SiLU + transpose (unchanged).
// ---------------------------------------------------------------------------
__global__ __launch_bounds__(256) void conv_tr_kernel(
    const float* __restrict__ x, const float* __restrict__ cw,
    const float* __restrict__ cb, const float* __restrict__ dt,
    float* __restrict__ u, float* __restrict__ dt_t,
    float* __restrict__ dtu_t) {
  __shared__ float Tdt[32][33];
  __shared__ float Tdu[32][33];
  const int tx = threadIdx.x;
  const int ty = threadIdx.y;
  const int b = blockIdx.z;
  const int i0 = blockIdx.y * 32;
  const int l0 = blockIdx.x * 32;
  const int gi = i0 + tx;
  const float cbv = cb[gi];
  const float cw0 = cw[gi * 4 + 0], cw1 = cw[gi * 4 + 1];
  const float cw2 = cw[gi * 4 + 2], cw3 = cw[gi * 4 + 3];
#pragma unroll
  for (int r = 0; r < 4; ++r) {
    const int l = l0 + ty + 8 * r;
    float acc = cbv;
    const float x3 = x[(b * L_SZ + l) * D_SZ + gi];
    const float x2 = (l >= 1) ? x[(b * L_SZ + l - 1) * D_SZ + gi] : 0.f;
    const float x1 = (l >= 2) ? x[(b * L_SZ + l - 2) * D_SZ + gi] : 0.f;
    const float x0 = (l >= 3) ? x[(b * L_SZ + l - 3) * D_SZ + gi] : 0.f;
    acc = fmaf(x0, cw0, acc);
    acc = fmaf(x1, cw1, acc);
    acc = fmaf(x2, cw2, acc);
    acc = fmaf(x3, cw3, acc);
    const float uv = acc / (1.f + __expf(-acc));
    const int off = (b * L_SZ + l) * D_SZ + gi;
    u[off] = uv;
    const float dtv = dt[off];
    Tdt[ty + 8 * r][tx] = dtv;
    Tdu[ty + 8 * r][tx] = dtv * uv;
  }
  __syncthreads();
#pragma unroll
  for (int r = 0; r < 4; ++r) {
    const int il = ty + 8 * r;
    const int off = (b * D_SZ + i0 + il) * L_SZ + l0 + tx;
    dt_t[off] = Tdt[tx][il];
    dtu_t[off] = Tdu[tx][il];
  }
}

// ---------------------------------------------------------------------------
// Selective scan v23 = v22 unchanged (v19's SMEM skeleton + packed Cm via
// plain C dereferences, compiler-managed waitcnts). The v20-22 NaNs were
// produced UPSTREAM (GEMM2 epilogue hazard) — scan logic was never wrong.
// ---------------------------------------------------------------------------
struct SChunk {
  f32x4 d0, d1, u0, u1;  // dt[0..7], dtu[0..7] in SGPRs
};

#define SLOAD_CHUNK(S, SDT, SDU)                                               \
  asm volatile("s_load_dwordx4 %0, %4, 0x0\n\t"                                \
               "s_load_dwordx4 %1, %4, 0x10\n\t"                               \
               "s_load_dwordx4 %2, %5, 0x0\n\t"                                \
               "s_load_dwordx4 %3, %5, 0x10"                                   \
               : "=&s"(S.d0), "=&s"(S.d1), "=&s"(S.u0), "=&s"(S.u1)            \
               : "s"(SDT), "s"(SDU));

#define SWAIT(S)                                                               \
  asm volatile("s_waitcnt lgkmcnt(0)"                                          \
               : "+s"(S.d0), "+s"(S.d1), "+s"(S.u0), "+s"(S.u1))

#define SADV()                                                                 \
  { sdt += 8; sdu += 8; }

__global__ __launch_bounds__(64, 4) void scan_kernel(
    const float* __restrict__ A_log, const float* __restrict__ dt_t,
    const float* __restrict__ dtu_t, const float* __restrict__ Bm,
    const u32x2* __restrict__ Cmq, float* __restrict__ part) {
  // XCD-aware remap (v12-proven): xcd = bid&7 owns contiguous sids.
  const int bid = blockIdx.x;        // 0..4607
  const int xcd = bid & 7;
  const int slot = bid >> 3;         // 0..575 within this XCD
  const int sid = xcd * 96 + slot / 6;
  const int w = slot % 6;            // j-split
  const int lane = threadIdx.x;      // 0..63
  const int b = sid / D_SZ;
  const int i = sid % D_SZ;
  const int j = w * 64 + lane;

  const float a2 = -__expf(A_log[i * S_SZ + j]) * LOG2E;
  const float bw = Bm[(b * D_SZ + i) * S_SZ + j];
  float h = 0.f;

  const float* sdt = dt_t + (b * D_SZ + i) * L_SZ;   // uniform -> SMEM
  const float* sdu = dtu_t + (b * D_SZ + i) * L_SZ;  // uniform -> SMEM
  // Packed Cm: u32x2 index (b*96 + l/4)*384 + j. Chunk c = groups 2c,2c+1:
  // qa at cq[0], qb at cq[384]; advance 768 per chunk.
  const u32x2* cq = Cmq + (b * 96) * 384 + j;

  // fold result mapping: lane r holds value s = (b3<<2)|(b2<<1)|b0 of chunk;
  // lanes with bits {1,4,5} == 0 store (8 lanes cover s=0..7).
  const int sq = (((lane >> 3) & 1) << 2) | (((lane >> 2) & 1) << 1) | (lane & 1);
  const bool storer = (lane & 0x32) == 0;
  float* pstore = part + ((w * B_SZ + b) * D_SZ + i) * L_SZ + sq;

  auto compute_chunk = [&](u32x2 qa_c, u32x2 qb_c, SChunk& S) {
    float acc[8];
    const float dts[8] = {S.d0[0], S.d0[1], S.d0[2], S.d0[3],
                          S.d1[0], S.d1[1], S.d1[2], S.d1[3]};
    const float dus[8] = {S.u0[0], S.u0[1], S.u0[2], S.u0[3],
                          S.u1[0], S.u1[1], S.u1[2], S.u1[3]};
    const unsigned int qs[4] = {qa_c[0], qa_c[1], qb_c[0], qb_c[1]};
#pragma unroll
    for (int s = 0; s < 8; ++s) {
      const float e = fexp2(dts[s] * a2);
      h = fmaf(e, h, bw * dus[s]);
      // bf16 pair unpack: even l = low half <<16, odd l = high half masked
      const unsigned int cw32 =
          (s & 1) ? (qs[s >> 1] & 0xFFFF0000u) : (qs[s >> 1] << 16);
      acc[s] = h * __uint_as_float(cw32);
    }
    // fold stage 1: pairing xor15 (row_mirror), side bit3, n2=4
    {
      const bool hi = (lane & 8) != 0;
#pragma unroll
      for (int q = 0; q < 4; ++q) {
        const float keep = hi ? acc[q + 4] : acc[q];
        const float send = hi ? acc[q] : acc[q + 4];
        acc[q] = keep + dpp_mov<0x140>(send);
      }
    }
    // fold stage 2: pairing xor7 (row_half_mirror), side bit2, n2=2
    {
      const bool hi = (lane & 4) != 0;
#pragma unroll
      for (int q = 0; q < 2; ++q) {
        const float keep = hi ? acc[q + 2] : acc[q];
        const float send = hi ? acc[q] : acc[q + 2];
        acc[q] = keep + dpp_mov<0x141>(send);
      }
    }
    // fold stage 3: pairing xor1 (quad_perm [1,0,3,2]), side bit0, n2=1
    {
      const bool hi = (lane & 1) != 0;
      const float keep = hi ? acc[1] : acc[0];
      const float send = hi ? acc[0] : acc[1];
      acc[0] = keep + dpp_mov<0xB1>(send);
    }
    // finish across unused bits {1,4,5}: all VALU-pipe lane exchanges
    float r = acc[0];
    r += dpp_mov<0x4E>(r);   // xor2: quad_perm [2,3,0,1]
    r = fold_xor16(r);       // xor16: permlane16_swap builtin
    r = fold_xor32(r);       // xor32: permlane32_swap builtin
    if (storer) *pstore = r;
    pstore += 8;
  };

  SChunk S0, S1;
  u32x2 qa = cq[0], qb = cq[384];    // chunk 0 (compiler-managed loads)
  cq += 768;
  SLOAD_CHUNK(S0, sdt, sdu); SADV(); // chunk 0 (SMEM)

  // STEP(c): issue chunk c+1's Cm loads (compiler schedules them early and
  // inserts its own waitcnt at first use); drain+reissue SMEM; compute
  // chunk c; rotate.
#define STEP(SC, SN)                                                           \
  {                                                                            \
    const u32x2 qa_n = cq[0];                                                  \
    const u32x2 qb_n = cq[384];                                                \
    cq += 768;                                                                 \
    SWAIT(SC);                                                                 \
    SLOAD_CHUNK(SN, sdt, sdu);                                                 \
    SADV();                                                                    \
    compute_chunk(qa, qb, SC);                                                 \
    qa = qa_n;                                                                 \
    qb = qb_n;                                                                 \
  }

#pragma unroll 1
  for (int it = 0; it < 8; ++it) {   // 6 chunks/iter: S alternation closes
    STEP(S0, S1);
    STEP(S1, S0);
    STEP(S0, S1);
    STEP(S1, S0);
    STEP(S0, S1);
    STEP(S1, S0);
  }
#undef STEP
  // 48 chunks computed. The final prefetch loads are dead (DCE'd by the
  // compiler); the dangling SMEM prefetch writes dead SGPRs and reads
  // valid workspace. Kernel ends here — no code after the loop (v16).
}

// ---------------------------------------------------------------------------
// Combine + transpose: y[b,l,i] = sum_{w<6} part[w][b][i][l] + u[b,l,i]*D[i]
// ---------------------------------------------------------------------------
__global__ __launch_bounds__(256) void combine_kernel(
    const float* __restrict__ part, const float* __restrict__ u,
    const float* __restrict__ Dv, float* __restrict__ y) {
  __shared__ float T[32][33];
  const int tx = threadIdx.x;
  const int ty0 = threadIdx.y;
  const int b = blockIdx.z;
  const int i0 = blockIdx.y * 32;
  const int l0 = blockIdx.x * 32;
#pragma unroll
  for (int r = 0; r < 4; ++r) {
    const int il = ty0 + 8 * r;
    float s = 0.f;
#pragma unroll
    for (int w = 0; w < 6; ++w)
      s += part[((w * B_SZ + b) * D_SZ + i0 + il) * L_SZ + l0 + tx];
    T[il][tx] = s;
  }
  __syncthreads();
#pragma unroll
  for (int r = 0; r < 4; ++r) {
    const int ll = ty0 + 8 * r;
    const int gi = i0 + tx;
    const int off = (b * L_SZ + l0 + ll) * D_SZ + gi;
    y[off] = fmaf(u[off], Dv[gi], T[tx][ll]);
  }
}

extern "C" void kernel_launch(void* const* d_in, const int* in_sizes, int n_in,
                              void* d_out, int out_size, void* d_ws,
                              size_t ws_size, hipStream_t stream) {
  const float* x = (const float*)d_in[0];
  const float* A_log = (const float*)d_in[1];
  const float* D = (const float*)d_in[2];
  const float* dt_w = (const float*)d_in[3];
  const float* dt_b = (const float*)d_in[4];
  const float* B_w = (const float*)d_in[5];
  const float* C_w = (const float*)d_in[6];
  const float* conv_w = (const float*)d_in[7];
  const float* conv_b = (const float*)d_in[8];
  float* y = (float*)d_out;

  float* ws = (float*)d_ws;
  float* dt = ws;                     // slot 0  [b,l,i]
  float* u = ws + TOT_ELEMS;          // slot 1
  float* Bm = ws + 2 * TOT_ELEMS;     // slot 2
  float* dt_t = ws + 3 * TOT_ELEMS;   // slot 3  [b,i,l]
  float* dtu_t = ws + 4 * TOT_ELEMS;  // slot 4  [b,i,l]
  float* part = ws + 5 * TOT_ELEMS;   // slots 5..10  [w][b][i][l], w<6
  unsigned short* bfarea = (unsigned short*)(ws + 11 * TOT_ELEMS);
  u32x2* Cmq = (u32x2*)bfarea;                 // 589824 B (packed bf16 Cm)
  unsigned short* xdblbf = bfarea + TOT_ELEMS; // 589824 B

  mfma_dual_gemm<1><<<dim3(24, 24), 128, 0, stream>>>(x, dt_w, B_w, dt_b, dt, xdblbf);
  mfma_dual_gemm<2><<<dim3(24, 24), 128, 0, stream>>>(xdblbf, B_w, C_w, nullptr, Bm, Cmq);
  conv_tr_kernel<<<dim3(L_SZ / 32, D_SZ / 32, B_SZ), dim3(32, 8), 0, stream>>>(
      x, conv_w, conv_b, dt, u, dt_t, dtu_t);
  scan_kernel<<<4608, 64, 0, stream>>>(A_log, dt_t, dtu_t, Bm, Cmq, part);
  combine_kernel<<<dim3(L_SZ / 32, D_SZ / 32, B_SZ), dim3(32, 8), 0, stream>>>(
      part, u, D, y);
}